// Round 17
// baseline (410.505 us; speedup 1.0000x reference)
//
#include <hip/hip_runtime.h>

#define NN 100000      // nodes
#define NE 1600000     // edges
#define C1 262144      // 64^3 cells (keyed as d2*64+child)
#define C2 4096        // 16^3 cells
#define BSH 7          // bucket shift (128 new-ids per bucket)
#define BSZ 128
#define NB 782         // ceil(NN/128)
#define PA_EDGES 2048
#define PA_IT (PA_EDGES / 256)
#define JMASK 0xFFFFF  // low 20 bits: compact j; bits 20..31: d2 of src cell
#define RMASK 0x1FFFF  // 17 bits: rank

// cell key layout: key = d2*64 + child, d2 = (x>>2)*256+(y>>2)*16+(z>>2),
// child = (x&3)*16+(y&3)*4+(z&3)
__device__ __forceinline__ void key2xyz(int key, float& x, float& y, float& z) {
    int d2 = key >> 6, ch = key & 63;
    x = (float)((((d2 >> 8) & 15) << 2) | (ch >> 4));
    y = (float)((((d2 >> 4) & 15) << 2) | ((ch >> 2) & 3));
    z = (float)(((d2 & 15) << 2) | (ch & 3));
}
__device__ __forceinline__ float4 max4(float4 a, float4 b) {
    return make_float4(fmaxf(a.x, b.x), fmaxf(a.y, b.y), fmaxf(a.z, b.z), fmaxf(a.w, b.w));
}
__device__ __forceinline__ float4 fma4(float s, float4 w, float4 acc) {
    return make_float4(s * w.x + acc.x, s * w.y + acc.y, s * w.z + acc.z, s * w.w + acc.w);
}

// ---------------- cell key of each node + node-per-cell histogram ----------------
__global__ __launch_bounds__(256)
void cidhist_k(const float* __restrict__ nodes, int* __restrict__ cid,
               int* __restrict__ cntN) {
    int i = blockIdx.x * 256 + threadIdx.x;
    if (i >= NN) return;
    int cx = min(max((int)floorf(nodes[3 * i]     * 0.25f), 0), 63);
    int cy = min(max((int)floorf(nodes[3 * i + 1] * 0.25f), 0), 63);
    int cz = min(max((int)floorf(nodes[3 * i + 2] * 0.25f), 0), 63);
    int d2 = ((cx >> 2) * 16 + (cy >> 2)) * 16 + (cz >> 2);
    int ch = ((cx & 3) * 4 + (cy & 3)) * 4 + (cz & 3);
    int key = (d2 << 6) | ch;
    cid[i] = key;
    atomicAdd(&cntN[key], 1);
}

// ---------------- generic exclusive scan: 2048/block. MODE 0: cnt[i]; MODE 1: cnt[i]>0 ----------------
template<int MODE>
__global__ __launch_bounds__(256)
void scan1_k(const int* __restrict__ cnt, int n, int* __restrict__ offs,
             int* __restrict__ bsum) {
    __shared__ int ws[4];
    int t = threadIdx.x, lane = t & 63, w = t >> 6;
    int base = blockIdx.x * 2048 + t * 8;
    int v[8]; int s = 0;
    #pragma unroll
    for (int i = 0; i < 8; ++i) {
        int raw = (base + i < n) ? cnt[base + i] : 0;
        v[i] = (MODE == 1) ? (raw > 0 ? 1 : 0) : raw;
        s += v[i];
    }
    int sc = s;
    #pragma unroll
    for (int off = 1; off < 64; off <<= 1) { int o = __shfl_up(sc, off); if (lane >= off) sc += o; }
    if (lane == 63) ws[w] = sc;
    __syncthreads();
    int wbase = 0;
    for (int i = 0; i < w; ++i) wbase += ws[i];
    int run = wbase + sc - s;
    #pragma unroll
    for (int i = 0; i < 8; ++i) { if (base + i < n) offs[base + i] = run; run += v[i]; }
    if (t == 255) bsum[blockIdx.x] = wbase + sc;
}

__global__ __launch_bounds__(256)
void scan2_k(int* __restrict__ bsum, int nb) {   // one block, nb <= 256
    __shared__ int ws[4];
    int t = threadIdx.x, lane = t & 63, w = t >> 6;
    int v = (t < nb) ? bsum[t] : 0;
    int sc = v;
    #pragma unroll
    for (int off = 1; off < 64; off <<= 1) { int o = __shfl_up(sc, off); if (lane >= off) sc += o; }
    if (lane == 63) ws[w] = sc;
    __syncthreads();
    int wbase = 0;
    for (int i = 0; i < w; ++i) wbase += ws[i];
    if (t < nb) bsum[t] = wbase + sc - v;
    if (t == 255) bsum[nb] = ws[0] + ws[1] + ws[2] + ws[3];
}

__global__ __launch_bounds__(256)
void scan3_k(int* __restrict__ offs, int n, const int* __restrict__ bsum, int nb) {
    int i = blockIdx.x * 256 + threadIdx.x;
    if (i < n) offs[i] += bsum[i >> 11];
    else if (i == n) offs[n] = bsum[nb];
}

// ---------------- occupied-cell compaction from offsOcc (deterministic, atomic-free) ----------------
__global__ __launch_bounds__(256)
void jlist_k(const int* __restrict__ offsOcc, int* __restrict__ jmap,
             int* __restrict__ oclist, int* __restrict__ ocount) {
    int c = blockIdx.x * 256 + threadIdx.x;
    if (c == 0) *ocount = offsOcc[C1];
    if (c >= C1) return;
    int pre = offsOcc[c];
    bool occ = offsOcc[c + 1] > pre;
    jmap[c] = occ ? pre : -1;
    if (occ) oclist[pre] = c;
}

// ---------------- node scatter: rank (new id) + nidx (old id by new id) ----------------
__global__ __launch_bounds__(256)
void nscatter_k(const int* __restrict__ cid, const int* __restrict__ offsN,
                int* __restrict__ cntN, int* __restrict__ rank, int* __restrict__ nidx) {
    int i = blockIdx.x * 256 + threadIdx.x;
    if (i >= NN) return;
    int c = cid[i];
    int pos = offsN[c] + atomicAdd(&cntN[c], -1) - 1;
    rank[i] = pos;
    nidx[pos] = i;
}

// ---------------- permute node data into new-id order ----------------
__global__ __launch_bounds__(256)
void permute_k(const int* __restrict__ nidx, const float* __restrict__ nodes,
               const float* __restrict__ feats, const int* __restrict__ cid,
               const int* __restrict__ jmap,
               float* __restrict__ pnodes, float* __restrict__ pfeat,
               int* __restrict__ jsrcP) {
    int d = blockIdx.x * 256 + threadIdx.x;
    if (d >= NN) return;
    int i = nidx[d];
    pnodes[3 * d]     = nodes[3 * i];
    pnodes[3 * d + 1] = nodes[3 * i + 1];
    pnodes[3 * d + 2] = nodes[3 * i + 2];
    pfeat[d] = feats[i];
    int c = cid[i];
    unsigned packed = (unsigned)jmap[c] | (((unsigned)c >> 6) << 20);  // j | d2<<20
    jsrcP[d] = (int)packed;
}

// ---------------- bucket histogram over rank[dst] (LDS pre-aggregated) ----------------
__global__ __launch_bounds__(256)
void bhist_k(const int* __restrict__ edst, const int* __restrict__ rank,
             int* __restrict__ btot) {
    __shared__ int h[NB];
    int tid = threadIdx.x;
    for (int i = tid; i < NB; i += 256) h[i] = 0;
    __syncthreads();
    int base = blockIdx.x * PA_EDGES;
    for (int i = 0; i < PA_IT; ++i) {
        int e = base + i * 256 + tid;
        if (e < NE) atomicAdd(&h[rank[edst[e]] >> BSH], 1);
    }
    __syncthreads();
    for (int i = tid; i < NB; i += 256) if (h[i]) atomicAdd(&btot[i], h[i]);
}

// one block: exclusive scan of NB (<=1024) bucket totals -> bbase[NB+1]; copy to cursor
__global__ __launch_bounds__(256)
void scanB_k(const int* __restrict__ btot, int* __restrict__ bbase,
             int* __restrict__ cursor) {
    __shared__ int ws[4];
    int t = threadIdx.x, lane = t & 63, w = t >> 6;
    int i0 = 4 * t;
    int v[4]; int s = 0;
    #pragma unroll
    for (int q = 0; q < 4; ++q) { v[q] = (i0 + q < NB) ? btot[i0 + q] : 0; s += v[q]; }
    int sc = s;
    #pragma unroll
    for (int off = 1; off < 64; off <<= 1) { int o = __shfl_up(sc, off); if (lane >= off) sc += o; }
    if (lane == 63) ws[w] = sc;
    __syncthreads();
    int wb = 0;
    for (int q = 0; q < w; ++q) wb += ws[q];
    int run = wb + sc - s;
    #pragma unroll
    for (int q = 0; q < 4; ++q) {
        if (i0 + q <= NB) { bbase[i0 + q] = run; if (i0 + q < NB) cursor[i0 + q] = run; }
        run += v[q];
    }
}

// ---------------- pass A: partition packed (rank_src | rd_low<<17) by dst bucket ----------------
__global__ __launch_bounds__(256)
void passA_k(const int* __restrict__ esrc, const int* __restrict__ edst,
             const int* __restrict__ rank, int* __restrict__ cursor,
             int* __restrict__ ebuf) {
    __shared__ int hist[NB];
    __shared__ int lofs[NB + 1];
    __shared__ int gbase[NB];
    __shared__ int cnt2[NB];
    __shared__ int stage[PA_EDGES];              // 8KB (packed)
    __shared__ unsigned short sbid[PA_EDGES];    // 4KB
    __shared__ int ws[4];
    int tid = threadIdx.x, lane = tid & 63, w = tid >> 6;
    for (int i = tid; i < NB; i += 256) { hist[i] = 0; cnt2[i] = 0; }
    __syncthreads();
    int base = blockIdx.x * PA_EDGES;
    for (int i = 0; i < PA_IT; ++i) {
        int e = base + i * 256 + tid;
        if (e < NE) atomicAdd(&hist[rank[edst[e]] >> BSH], 1);
    }
    __syncthreads();
    // exclusive scan hist -> lofs (4 per thread)
    int i0 = 4 * tid;
    int v[4]; int s = 0;
    #pragma unroll
    for (int q = 0; q < 4; ++q) { v[q] = (i0 + q < NB) ? hist[i0 + q] : 0; s += v[q]; }
    int sc = s;
    #pragma unroll
    for (int off = 1; off < 64; off <<= 1) { int o = __shfl_up(sc, off); if (lane >= off) sc += o; }
    if (lane == 63) ws[w] = sc;
    __syncthreads();
    int wb = 0;
    for (int q = 0; q < w; ++q) wb += ws[q];
    int run = wb + sc - s;
    #pragma unroll
    for (int q = 0; q < 4; ++q) {
        if (i0 + q <= NB) lofs[i0 + q] = run;
        run += v[q];
    }
    __syncthreads();
    for (int b = tid; b < NB; b += 256) {
        int c = hist[b];
        gbase[b] = c ? atomicAdd(&cursor[b], c) : 0;
    }
    __syncthreads();
    for (int i = 0; i < PA_IT; ++i) {
        int e = base + i * 256 + tid;
        if (e < NE) {
            int rd = rank[edst[e]], rs = rank[esrc[e]];
            int b = rd >> BSH;
            int p = lofs[b] + atomicAdd(&cnt2[b], 1);
            stage[p] = rs | ((rd & (BSZ - 1)) << 17);
            sbid[p] = (unsigned short)b;
        }
    }
    __syncthreads();
    int nval = min(PA_EDGES, NE - base);
    for (int k = tid; k < nval; k += 256) {
        int b = sbid[k];
        ebuf[gbase[b] + (k - lofs[b])] = stage[k];
    }
}

// ---------------- pass B: per-bucket final scatter; offs0 (new-id CSR); csrc fused ----------------
__global__ __launch_bounds__(256)
void passB_k(const int* __restrict__ ebuf, const int* __restrict__ bbase,
             const int* __restrict__ jsrcP,
             int* __restrict__ offs0, int* __restrict__ srcs0, int* __restrict__ csrc0) {
    __shared__ int cnt[BSZ];
    __shared__ int pos[BSZ];
    __shared__ int ws[4];
    int b = blockIdx.x, tid = threadIdx.x, lane = tid & 63, w = tid >> 6;
    int d0 = b << BSH;
    int range = min(BSZ, NN - d0);
    if (tid < BSZ) cnt[tid] = 0;
    __syncthreads();
    int r0 = bbase[b], r1 = bbase[b + 1];
    for (int k = r0 + tid; k < r1; k += 256) atomicAdd(&cnt[(ebuf[k] >> 17) & (BSZ - 1)], 1);
    __syncthreads();
    int v = (tid < BSZ) ? cnt[tid] : 0;
    int sc = v;
    #pragma unroll
    for (int off = 1; off < 64; off <<= 1) { int o = __shfl_up(sc, off); if (lane >= off) sc += o; }
    if (lane == 63) ws[w] = sc;
    __syncthreads();
    int wb = 0;
    for (int q = 0; q < w; ++q) wb += ws[q];
    int rel = wb + sc - v;                        // exclusive per-dst prefix
    if (tid < range) offs0[d0 + tid] = r0 + rel;
    if (tid == 0) offs0[min(d0 + BSZ, NN)] = r1;  // benign duplicate of next base
    if (tid < BSZ) pos[tid] = r0 + rel;
    __syncthreads();
    for (int k = r0 + tid; k < r1; k += 256) {
        int pk = ebuf[k];
        int di = (pk >> 17) & (BSZ - 1);
        int p = atomicAdd(&pos[di], 1);
        int rs = pk & RMASK;
        srcs0[p] = rs;
        csrc0[p] = jsrcP[rs];                     // packed j | d2<<20
    }
}

// ---------------- level-2 bitmap: contiguous edge slice -> LDS bitmap -> global ----------------
__global__ __launch_bounds__(256)
void mask_k(const int* __restrict__ offsN, const int* __restrict__ offs0,
            const int* __restrict__ csrc0,
            unsigned long long* __restrict__ mask, int* __restrict__ l2num) {
    __shared__ unsigned long long words[64];
    int d2 = blockIdx.x, tid = threadIdx.x;
    if (tid < 64) words[tid] = 0;
    __syncthreads();
    // all edges of d2's 64 child cells are one contiguous range (key ordering)
    int e0 = offs0[offsN[d2 << 6]];
    int e1 = offs0[offsN[(d2 + 1) << 6]];
    for (int t = e0 + tid; t < e1; t += 256) {
        int s2 = (int)(((unsigned)csrc0[t]) >> 20);
        atomicOr(&words[s2 >> 6], 1ull << (s2 & 63));
    }
    __syncthreads();
    if (tid < 64) {                                // wave 0 only
        unsigned long long wv = words[tid];
        mask[(size_t)d2 * 64 + tid] = wv;
        int pc = __popcll(wv);
        int sc = pc;
        #pragma unroll
        for (int off = 1; off < 64; off <<= 1) {
            int o = __shfl_up(sc, off);
            if (tid >= off) sc += o;
        }
        if (tid == 63) l2num[d2] = sc;
    }
}

// ---------------- emit compact per-d2 src list at deterministic offsets ----------------
__global__ __launch_bounds__(64)
void emit_k(const unsigned long long* __restrict__ mask, const int* __restrict__ l2off,
            int* __restrict__ l2src) {
    int d2 = blockIdx.x, tid = threadIdx.x;      // 64 threads
    unsigned long long wv = mask[(size_t)d2 * 64 + tid];
    int pc = __popcll(wv);
    int sc = pc;
    #pragma unroll
    for (int off = 1; off < 64; off <<= 1) {
        int o = __shfl_up(sc, off);
        if (tid >= off) sc += o;
    }
    int p = l2off[d2] + sc - pc;                 // exclusive prefix within d2
    while (wv) {
        int b = __builtin_ctzll(wv);
        wv &= wv - 1;
        l2src[p++] = (tid << 6) | b;
    }
}

// ---------------- level 0: h = f @ W_f + pos @ W_p (new-id space) ----------------
template<int CI, int CO>
__global__ __launch_bounds__(256)
void xform0_k(const float* __restrict__ pnodes, const float* __restrict__ f,
              const float* __restrict__ W, float* __restrict__ h) {
    __shared__ float sW[(CI + 3) * CO];
    for (int i = threadIdx.x; i < (CI + 3) * CO; i += 256) sW[i] = W[i];
    __syncthreads();
    int gid = blockIdx.x * 256 + threadIdx.x;
    int i = gid / CO, ch = gid - i * CO;
    if (i >= NN) return;
    float s = pnodes[3 * i] * sW[CI * CO + ch] + pnodes[3 * i + 1] * sW[(CI + 1) * CO + ch]
            + pnodes[3 * i + 2] * sW[(CI + 2) * CO + ch];
    #pragma unroll
    for (int k = 0; k < CI; ++k) s += f[(size_t)i * CI + k] * sW[k * CO + ch];
    h[(size_t)i * CO + ch] = s;
}

// fused: gather over W1 (8ch) + xform W2 (8->16) -> h2. Block covers 32 dst nodes.
__global__ __launch_bounds__(256)
void gatherL0f_k(const float* __restrict__ pnodes, const float* __restrict__ h1,
                 const float* __restrict__ W1pos,       // 3x8
                 const float* __restrict__ W2,          // 11x16
                 const int* __restrict__ offs, const int* __restrict__ srcs,
                 float* __restrict__ h2) {
    __shared__ float sW1[24];
    __shared__ float sW2[176];
    __shared__ float f1s[32][8];
    int tid = threadIdx.x;
    if (tid < 24) sW1[tid] = W1pos[tid];
    if (tid < 176) sW2[tid] = W2[tid];
    __syncthreads();
    int gid = blockIdx.x * 256 + tid;
    int d = gid >> 3, ch = gid & 7;
    int dbase = blockIdx.x * 32;
    if (d < NN) {
        float c = pnodes[3 * d] * sW1[ch] + pnodes[3 * d + 1] * sW1[8 + ch] + pnodes[3 * d + 2] * sW1[16 + ch];
        float m0 = c, m1 = c, m2 = c, m3 = c;
        int e0 = offs[d], e1 = offs[d + 1];
        int t = e0;
        for (; t + 4 <= e1; t += 4) {
            int s0 = srcs[t], s1 = srcs[t + 1], s2 = srcs[t + 2], s3 = srcs[t + 3];
            m0 = fmaxf(m0, h1[(size_t)s0 * 8 + ch]);
            m1 = fmaxf(m1, h1[(size_t)s1 * 8 + ch]);
            m2 = fmaxf(m2, h1[(size_t)s2 * 8 + ch]);
            m3 = fmaxf(m3, h1[(size_t)s3 * 8 + ch]);
        }
        for (; t < e1; ++t) m0 = fmaxf(m0, h1[(size_t)srcs[t] * 8 + ch]);
        f1s[d - dbase][ch] = fmaxf(fmaxf(m0, m1), fmaxf(m2, m3)) - c;
    }
    __syncthreads();
    // epilogue: h2[d][ch2] for 32 d x 16 ch2 = 512 outputs, 2 per thread
    #pragma unroll
    for (int rep = 0; rep < 2; ++rep) {
        int dL = (tid >> 4) + rep * 16, ch2 = tid & 15;
        int dg = dbase + dL;
        if (dg < NN) {
            float s = pnodes[3 * dg] * sW2[128 + ch2] + pnodes[3 * dg + 1] * sW2[144 + ch2]
                    + pnodes[3 * dg + 2] * sW2[160 + ch2];
            #pragma unroll
            for (int k = 0; k < 8; ++k) s += f1s[dL][k] * sW2[k * 16 + ch2];
            h2[(size_t)dg * 16 + ch2] = s;
        }
    }
}

// float4 gather, CO=16: 4 threads per dst node (channel quads)
__global__ __launch_bounds__(256)
void gatherL0v4_k(const float* __restrict__ pnodes, const float* __restrict__ h,
                  const float* __restrict__ Wpos,       // 3x16
                  const int* __restrict__ offs, const int* __restrict__ srcs,
                  float* __restrict__ out) {
    __shared__ float sW[48];
    int tid = threadIdx.x;
    if (tid < 48) sW[tid] = Wpos[tid];
    __syncthreads();
    int gid = blockIdx.x * 256 + tid;
    int d = gid >> 2, q = gid & 3;
    if (d >= NN) return;
    float px = pnodes[3 * d], py = pnodes[3 * d + 1], pz = pnodes[3 * d + 2];
    float4 w0 = *(const float4*)&sW[q * 4];
    float4 w1 = *(const float4*)&sW[16 + q * 4];
    float4 w2 = *(const float4*)&sW[32 + q * 4];
    float4 c = make_float4(px * w0.x + py * w1.x + pz * w2.x, px * w0.y + py * w1.y + pz * w2.y,
                           px * w0.z + py * w1.z + pz * w2.z, px * w0.w + py * w1.w + pz * w2.w);
    float4 m0 = c, m1 = c, m2 = c, m3 = c;       // no self-loop at level 0; empty -> 0
    int e0 = offs[d], e1 = offs[d + 1];
    int t = e0;
    for (; t + 4 <= e1; t += 4) {
        int s0 = srcs[t], s1 = srcs[t + 1], s2 = srcs[t + 2], s3 = srcs[t + 3];
        m0 = max4(m0, *(const float4*)&h[(size_t)s0 * 16 + q * 4]);
        m1 = max4(m1, *(const float4*)&h[(size_t)s1 * 16 + q * 4]);
        m2 = max4(m2, *(const float4*)&h[(size_t)s2 * 16 + q * 4]);
        m3 = max4(m3, *(const float4*)&h[(size_t)s3 * 16 + q * 4]);
    }
    for (; t < e1; ++t) m0 = max4(m0, *(const float4*)&h[(size_t)srcs[t] * 16 + q * 4]);
    float4 m = max4(max4(m0, m1), max4(m2, m3));
    *(float4*)&out[(size_t)d * 16 + q * 4] = make_float4(m.x - c.x, m.y - c.y, m.z - c.z, m.w - c.w);
}

// ---------------- level 1: fused pool(16ch) + xform W3 -> Hc ----------------
__global__ __launch_bounds__(256)
void pxformL1_k(const float* __restrict__ f2, const int* __restrict__ offsN,
                const int* __restrict__ oclist, const int* __restrict__ ocount,
                const float* __restrict__ W3, float* __restrict__ h) {
    __shared__ float sW[19 * 32];
    __shared__ float nf[8][16];
    for (int i = threadIdx.x; i < 19 * 32; i += 256) sW[i] = W3[i];
    int gid = blockIdx.x * 256 + threadIdx.x;
    int j = gid >> 5, ch = gid & 31;
    int lj = threadIdx.x >> 5;                   // 8 js per block
    bool valid = j < *ocount;
    int d = valid ? oclist[j] : 0;
    if (valid && ch < 16) {
        float m = 0.f;                           // f2 >= 0 (post-relu)
        int n0 = offsN[d], n1 = offsN[d + 1];
        for (int n = n0; n < n1; ++n) m = fmaxf(m, f2[(size_t)n * 16 + ch]);
        nf[lj][ch] = m;
    }
    __syncthreads();
    if (!valid) return;
    float px, py, pz;
    key2xyz(d, px, py, pz);
    float s = px * sW[16 * 32 + ch] + py * sW[17 * 32 + ch] + pz * sW[18 * 32 + ch];
    #pragma unroll
    for (int k = 0; k < 16; ++k) s += nf[lj][k] * sW[k * 32 + ch];
    h[(size_t)j * 32 + ch] = s;
}

// fused float4 gather(W3pos) + xform W4 (32->32) -> hnext (different buffer).
__global__ __launch_bounds__(256)
void gatherL1f_k(const float* __restrict__ h, const float* __restrict__ W3pos,
                 const float* __restrict__ W4,          // 35x32
                 const int* __restrict__ offsN, const int* __restrict__ offs0,
                 const int* __restrict__ csrc0,
                 const int* __restrict__ oclist, const int* __restrict__ ocount,
                 float* __restrict__ hnext) {
    __shared__ float sWp[96];
    __shared__ float sW4[35 * 32];
    __shared__ float gsT[32][33];                // [ch][lj], padded
    int tid = threadIdx.x;
    if (tid < 96) sWp[tid] = W3pos[tid];
    for (int i = tid; i < 35 * 32; i += 256) sW4[i] = W4[i];
    __syncthreads();
    int gid = blockIdx.x * 256 + tid;
    int j = gid >> 3, q = gid & 7;
    int lj = tid >> 3;
    bool valid = j < *ocount;
    float px = 0, py = 0, pz = 0;
    if (valid) {
        int d = oclist[j];
        key2xyz(d, px, py, pz);
        float4 w0 = *(const float4*)&sWp[q * 4];
        float4 w1 = *(const float4*)&sWp[32 + q * 4];
        float4 w2 = *(const float4*)&sWp[64 + q * 4];
        float4 c = make_float4(px * w0.x + py * w1.x + pz * w2.x, px * w0.y + py * w1.y + pz * w2.y,
                               px * w0.z + py * w1.z + pz * w2.z, px * w0.w + py * w1.w + pz * w2.w);
        float4 self = *(const float4*)&h[(size_t)j * 32 + q * 4];
        float4 m0 = max4(c, self), m1 = m0, m2 = m0, m3 = m0;   // self-loop
        int e0 = offs0[offsN[d]], e1 = offs0[offsN[d + 1]];
        int t = e0;
        for (; t + 4 <= e1; t += 4) {
            int s0 = csrc0[t] & JMASK, s1 = csrc0[t + 1] & JMASK;
            int s2 = csrc0[t + 2] & JMASK, s3 = csrc0[t + 3] & JMASK;
            m0 = max4(m0, *(const float4*)&h[(size_t)s0 * 32 + q * 4]);
            m1 = max4(m1, *(const float4*)&h[(size_t)s1 * 32 + q * 4]);
            m2 = max4(m2, *(const float4*)&h[(size_t)s2 * 32 + q * 4]);
            m3 = max4(m3, *(const float4*)&h[(size_t)s3 * 32 + q * 4]);
        }
        for (; t < e1; ++t) m0 = max4(m0, *(const float4*)&h[(size_t)(csrc0[t] & JMASK) * 32 + q * 4]);
        float4 m = max4(max4(m0, m1), max4(m2, m3));
        gsT[q * 4 + 0][lj] = m.x - c.x;
        gsT[q * 4 + 1][lj] = m.y - c.y;
        gsT[q * 4 + 2][lj] = m.z - c.z;
        gsT[q * 4 + 3][lj] = m.w - c.w;
    }
    __syncthreads();
    if (!valid) return;
    float4 s4;
    {
        float4 w0 = *(const float4*)&sW4[32 * 32 + q * 4];
        float4 w1 = *(const float4*)&sW4[33 * 32 + q * 4];
        float4 w2 = *(const float4*)&sW4[34 * 32 + q * 4];
        s4 = make_float4(px * w0.x + py * w1.x + pz * w2.x, px * w0.y + py * w1.y + pz * w2.y,
                         px * w0.z + py * w1.z + pz * w2.z, px * w0.w + py * w1.w + pz * w2.w);
    }
    #pragma unroll
    for (int k = 0; k < 32; ++k) {
        float g = gsT[k][lj];
        s4 = fma4(g, *(const float4*)&sW4[k * 32 + q * 4], s4);
    }
    *(float4*)&hnext[(size_t)j * 32 + q * 4] = s4;
}

// plain float4 flat gather (final level-1 layer)
__global__ __launch_bounds__(256)
void gatherL1_k(const float* __restrict__ h, const float* __restrict__ Wpos,
                const int* __restrict__ offsN, const int* __restrict__ offs0,
                const int* __restrict__ csrc0,
                const int* __restrict__ oclist, const int* __restrict__ ocount,
                float* __restrict__ g) {
    __shared__ float sW[96];
    int tid = threadIdx.x;
    if (tid < 96) sW[tid] = Wpos[tid];
    __syncthreads();
    int gid = blockIdx.x * 256 + tid;
    int j = gid >> 3, q = gid & 7;
    if (j >= *ocount) return;
    int d = oclist[j];
    float px, py, pz;
    key2xyz(d, px, py, pz);
    float4 w0 = *(const float4*)&sW[q * 4];
    float4 w1 = *(const float4*)&sW[32 + q * 4];
    float4 w2 = *(const float4*)&sW[64 + q * 4];
    float4 c = make_float4(px * w0.x + py * w1.x + pz * w2.x, px * w0.y + py * w1.y + pz * w2.y,
                           px * w0.z + py * w1.z + pz * w2.z, px * w0.w + py * w1.w + pz * w2.w);
    float4 self = *(const float4*)&h[(size_t)j * 32 + q * 4];
    float4 m0 = max4(c, self), m1 = m0, m2 = m0, m3 = m0;   // self-loop
    int e0 = offs0[offsN[d]], e1 = offs0[offsN[d + 1]];
    int t = e0;
    for (; t + 4 <= e1; t += 4) {
        int s0 = csrc0[t] & JMASK, s1 = csrc0[t + 1] & JMASK;
        int s2 = csrc0[t + 2] & JMASK, s3 = csrc0[t + 3] & JMASK;
        m0 = max4(m0, *(const float4*)&h[(size_t)s0 * 32 + q * 4]);
        m1 = max4(m1, *(const float4*)&h[(size_t)s1 * 32 + q * 4]);
        m2 = max4(m2, *(const float4*)&h[(size_t)s2 * 32 + q * 4]);
        m3 = max4(m3, *(const float4*)&h[(size_t)s3 * 32 + q * 4]);
    }
    for (; t < e1; ++t) m0 = max4(m0, *(const float4*)&h[(size_t)(csrc0[t] & JMASK) * 32 + q * 4]);
    float4 m = max4(max4(m0, m1), max4(m2, m3));
    *(float4*)&g[(size_t)j * 32 + q * 4] = make_float4(m.x - c.x, m.y - c.y, m.z - c.z, m.w - c.w);
}

// ---------------- level 2 (block per 16^3 cell) ----------------
// children of d2 are the contiguous key range [d2*64, d2*64+64)
__global__ __launch_bounds__(256)
void pool2x_k(const float* __restrict__ Gc, const int* __restrict__ jmap,
              const float* __restrict__ W5, float* __restrict__ h5) {
    __shared__ float part[8][32];
    __shared__ float nf2row[32];
    int d2 = blockIdx.x, tid = threadIdx.x;
    int x2 = d2 >> 8, y2 = (d2 >> 4) & 15, z2 = d2 & 15;
    int ch = tid & 31, grp = tid >> 5;                 // 8 grps x 8 children
    float m = 0.f;
    #pragma unroll
    for (int cc = 0; cc < 8; ++cc) {
        int cj = jmap[(d2 << 6) | (grp * 8 + cc)];
        if (cj >= 0) m = fmaxf(m, Gc[(size_t)cj * 32 + ch]);
    }
    part[grp][ch] = m;
    __syncthreads();
    if (tid < 32) {
        float mm = part[0][tid];
        #pragma unroll
        for (int g = 1; g < 8; ++g) mm = fmaxf(mm, part[g][tid]);
        nf2row[tid] = mm;
    }
    __syncthreads();
    if (tid < 64) {
        float s = x2 * W5[32 * 64 + tid] + y2 * W5[33 * 64 + tid] + z2 * W5[34 * 64 + tid];
        #pragma unroll
        for (int k = 0; k < 32; ++k) s += nf2row[k] * W5[k * 64 + tid];
        h5[(size_t)d2 * 64 + tid] = s;
    }
}

// level-2 gconv via flat adjacency list, float4 (+ optional fused next xform). One block per d2.
template<bool FUSE, bool WRITE_G>
__global__ __launch_bounds__(256)
void gconvL2_k(const float* __restrict__ h, const float* __restrict__ Wpos,
               const int* __restrict__ l2off, const int* __restrict__ l2src,
               const float* __restrict__ Wn,           // (64+3)x64, if FUSE
               float* __restrict__ gout, float* __restrict__ hnext) {
    __shared__ float red[16][64];
    __shared__ float grow[64];
    int d2 = blockIdx.x, tid = threadIdx.x;
    int x2 = d2 >> 8, y2 = (d2 >> 4) & 15, z2 = d2 & 15;
    int q = tid & 15, grp = tid >> 4;                  // 16 groups split the list
    int n0 = l2off[d2], num = l2off[d2 + 1] - n0;
    int per = (num + 15) >> 4;
    int s = n0 + grp * per;
    int e = min(n0 + num, s + per);
    float4 m0 = make_float4(-1e30f, -1e30f, -1e30f, -1e30f);
    float4 m1 = m0, m2 = m0, m3 = m0;
    int t = s;
    for (; t + 4 <= e; t += 4) {
        int s0 = l2src[t], s1 = l2src[t + 1], s2 = l2src[t + 2], s3 = l2src[t + 3];
        m0 = max4(m0, *(const float4*)&h[(size_t)s0 * 64 + q * 4]);
        m1 = max4(m1, *(const float4*)&h[(size_t)s1 * 64 + q * 4]);
        m2 = max4(m2, *(const float4*)&h[(size_t)s2 * 64 + q * 4]);
        m3 = max4(m3, *(const float4*)&h[(size_t)s3 * 64 + q * 4]);
    }
    for (; t < e; ++t) m0 = max4(m0, *(const float4*)&h[(size_t)l2src[t] * 64 + q * 4]);
    float4 m = max4(max4(m0, m1), max4(m2, m3));
    red[grp][q * 4 + 0] = m.x;
    red[grp][q * 4 + 1] = m.y;
    red[grp][q * 4 + 2] = m.z;
    red[grp][q * 4 + 3] = m.w;
    __syncthreads();
    if (tid < 64) {
        int ch = tid;
        float mm = red[0][ch];
        #pragma unroll
        for (int g = 1; g < 16; ++g) mm = fmaxf(mm, red[g][ch]);
        float c = x2 * Wpos[ch] + y2 * Wpos[64 + ch] + z2 * Wpos[128 + ch];
        mm = fmaxf(mm, fmaxf(c, h[(size_t)d2 * 64 + ch]));   // self-loop + empty
        float g = mm - c;
        if (WRITE_G) gout[(size_t)d2 * 64 + ch] = g;
        if (FUSE) grow[ch] = g;
    }
    if (FUSE) {
        __syncthreads();
        if (tid < 64) {
            float s2v = x2 * Wn[64 * 64 + tid] + y2 * Wn[65 * 64 + tid] + z2 * Wn[66 * 64 + tid];
            #pragma unroll
            for (int k = 0; k < 64; ++k) s2v += grow[k] * Wn[k * 64 + tid];
            hnext[(size_t)d2 * 64 + tid] = s2v;
        }
    }
}

// ---------------- output pool + linear ----------------
__global__ __launch_bounds__(256)
void outpool_k(const float* __restrict__ g7, float* __restrict__ xo) {
    int gid = blockIdx.x * 256 + threadIdx.x;
    if (gid >= 64 * 64) return;
    int oc = gid >> 6, ch = gid & 63;
    int cx = oc >> 4, cy = (oc >> 2) & 3, cz = oc & 3;
    float m = 0.f;
    for (int tc = 0; tc < 64; ++tc) {
        int i = tc >> 4, j = (tc >> 2) & 3, k = tc & 3;
        int d2 = ((cx * 4 + i) * 16 + (cy * 4 + j)) * 16 + (cz * 4 + k);
        m = fmaxf(m, g7[(size_t)d2 * 64 + ch]);
    }
    xo[(size_t)oc * 64 + ch] = m;
}

__global__ __launch_bounds__(64)
void linear_k(const float* __restrict__ xo, const float* __restrict__ Wl,
              const float* __restrict__ bl, float* __restrict__ out) {
    int j = blockIdx.x;
    float s = 0.f;
    for (int i = threadIdx.x; i < 4096; i += 64) s += xo[i] * Wl[(size_t)i * 100 + j];
    #pragma unroll
    for (int off = 32; off; off >>= 1) s += __shfl_down(s, off);
    if (threadIdx.x == 0) out[j] = s + bl[j];
}

extern "C" void kernel_launch(void* const* d_in, const int* in_sizes, int n_in,
                              void* d_out, int out_size, void* d_ws, size_t ws_size,
                              hipStream_t stream) {
    (void)in_sizes; (void)n_in; (void)out_size;
    const float* nodes = (const float*)d_in[0];
    const float* feats = (const float*)d_in[1];
    const int*   edges = (const int*)d_in[2];
    const int*   esrc  = edges;
    const int*   edst  = edges + NE;
    const float* W1 = (const float*)d_in[3];
    const float* W2 = (const float*)d_in[4];
    const float* W3 = (const float*)d_in[5];
    const float* W4 = (const float*)d_in[6];
    const float* W5 = (const float*)d_in[7];
    const float* W6 = (const float*)d_in[8];
    const float* W7 = (const float*)d_in[9];
    const float* Wl = (const float*)d_in[10];
    const float* bl = (const float*)d_in[11];
    float* out = (float*)d_out;

    char* ws = (char*)d_ws;
    size_t off = 0;
    auto alloc = [&](size_t bytes) { void* p = ws + off; off = (off + bytes + 255) & ~(size_t)255; return p; };
    // zero region: cntN + btot (one memset)
    int*   cntN    = (int*)alloc((size_t)C1 * 4);
    int*   btot    = (int*)alloc((size_t)NB * 4);
    size_t zero_bytes = off;
    int*   ocount  = (int*)alloc(4);
    int*   bsum   = (int*)alloc(260 * 4);
    int*   bbase  = (int*)alloc((size_t)(NB + 1) * 4);
    int*   cursor = (int*)alloc((size_t)NB * 4);
    int*   cid    = (int*)alloc((size_t)NN * 4);
    int*   rank   = (int*)alloc((size_t)NN * 4);
    int*   nidx   = (int*)alloc((size_t)NN * 4);
    int*   offsOcc= (int*)alloc((size_t)(C1 + 1) * 4);
    int*   offsN  = (int*)alloc((size_t)(C1 + 1) * 4);
    int*   offs0  = (int*)alloc((size_t)(NN + 1) * 4);
    int*   srcs0  = (int*)alloc((size_t)NE * 4);
    int*   csrc0  = (int*)alloc((size_t)NE * 4);
    int*   ebuf   = (int*)alloc((size_t)NE * 4);
    int*   oclist = (int*)alloc((size_t)NN * 4);
    int*   jmap   = (int*)alloc((size_t)C1 * 4);
    int*   jsrcP  = (int*)alloc((size_t)NN * 4);
    unsigned long long* mask = (unsigned long long*)alloc((size_t)C2 * 64 * 8);  // 2MB
    int*   l2num  = (int*)alloc((size_t)C2 * 4);
    int*   l2off  = (int*)alloc((size_t)(C2 + 1) * 4);
    int*   l2srcA = (int*)alloc((size_t)NE * 4);
    float* pnodes = (float*)alloc((size_t)NN * 3 * 4);
    float* pfeat  = (float*)alloc((size_t)NN * 4);
    float* A      = (float*)alloc((size_t)NN * 48 * 4);   // h1, h2, f2
    float* Hc     = (float*)alloc((size_t)NN * 32 * 4);
    float* Gc     = (float*)alloc((size_t)NN * 32 * 4);
    float* h5     = (float*)alloc((size_t)C2 * 64 * 4);
    float* h6     = (float*)alloc((size_t)C2 * 64 * 4);
    float* h7     = (float*)alloc((size_t)C2 * 64 * 4);
    float* g7     = (float*)alloc((size_t)C2 * 64 * 4);
    float* xo     = (float*)alloc((size_t)64 * 64 * 4);
    if (ws_size < off) return;

    float* h1 = A;                      // [NN][8]
    float* h2 = A + (size_t)NN * 16;    // [NN][16]
    float* f2 = A + (size_t)NN * 32;    // [NN][16]

    hipMemsetAsync(cntN, 0, zero_bytes, stream);

    auto gr = [](long long n) { return (int)((n + 255) / 256); };
    const int nbC1 = (C1 + 2047) / 2048;   // 128
    const int nbC2 = (C2 + 2047) / 2048;   // 2
    const int gPA  = (NE + PA_EDGES - 1) / PA_EDGES;  // 782

    // ---- connectivity build (key space, atomic-cursor-free) ----
    cidhist_k<<<gr(NN), 256, 0, stream>>>(nodes, cid, cntN);
    // occupancy compaction via boolean scan
    scan1_k<1><<<nbC1, 256, 0, stream>>>(cntN, C1, offsOcc, bsum);
    scan2_k<<<1, 256, 0, stream>>>(bsum, nbC1);
    scan3_k<<<gr(C1 + 1), 256, 0, stream>>>(offsOcc, C1, bsum, nbC1);
    jlist_k<<<gr(C1), 256, 0, stream>>>(offsOcc, jmap, oclist, ocount);
    // node CSR offsets
    scan1_k<0><<<nbC1, 256, 0, stream>>>(cntN, C1, offsN, bsum);
    scan2_k<<<1, 256, 0, stream>>>(bsum, nbC1);
    scan3_k<<<gr(C1 + 1), 256, 0, stream>>>(offsN, C1, bsum, nbC1);
    nscatter_k<<<gr(NN), 256, 0, stream>>>(cid, offsN, cntN, rank, nidx);
    permute_k<<<gr(NN), 256, 0, stream>>>(nidx, nodes, feats, cid, jmap, pnodes, pfeat, jsrcP);
    bhist_k<<<gPA, 256, 0, stream>>>(edst, rank, btot);
    scanB_k<<<1, 256, 0, stream>>>(btot, bbase, cursor);
    passA_k<<<gPA, 256, 0, stream>>>(esrc, edst, rank, cursor, ebuf);
    passB_k<<<NB, 256, 0, stream>>>(ebuf, bbase, jsrcP, offs0, srcs0, csrc0);
    // level-2 adjacency: bitmap -> scan -> deterministic emit
    mask_k<<<C2, 256, 0, stream>>>(offsN, offs0, csrc0, mask, l2num);
    scan1_k<0><<<nbC2, 256, 0, stream>>>(l2num, C2, l2off, bsum);
    scan2_k<<<1, 256, 0, stream>>>(bsum, nbC2);
    scan3_k<<<gr(C2 + 1), 256, 0, stream>>>(l2off, C2, bsum, nbC2);
    emit_k<<<C2, 64, 0, stream>>>(mask, l2off, l2srcA);

    // ---- level 0 (rank space) ----
    xform0_k<1, 8><<<gr((long long)NN * 8), 256, 0, stream>>>(pnodes, pfeat, W1, h1);
    gatherL0f_k<<<gr((long long)NN * 8), 256, 0, stream>>>(pnodes, h1, W1 + 1 * 8, W2, offs0, srcs0, h2);
    gatherL0v4_k<<<gr((long long)NN * 4), 256, 0, stream>>>(pnodes, h2, W2 + 8 * 16, offs0, srcs0, f2);

    // ---- level 1 (compact occupied cells, flat edge ranges; ping-pong Hc/Gc) ----
    pxformL1_k<<<gr((long long)NN * 32), 256, 0, stream>>>(f2, offsN, oclist, ocount, W3, Hc);
    gatherL1f_k<<<gr((long long)NN * 8), 256, 0, stream>>>(Hc, W3 + 16 * 32, W4, offsN, offs0, csrc0, oclist, ocount, Gc);
    gatherL1_k<<<gr((long long)NN * 8), 256, 0, stream>>>(Gc, W4 + 32 * 32, offsN, offs0, csrc0, oclist, ocount, Hc);

    // ---- level 2 (block per 16^3 cell, list-driven, fused) ----
    pool2x_k<<<C2, 256, 0, stream>>>(Hc, jmap, W5, h5);
    gconvL2_k<true,  false><<<C2, 256, 0, stream>>>(h5, W5 + 32 * 64, l2off, l2srcA, W6, nullptr, h6);
    gconvL2_k<true,  false><<<C2, 256, 0, stream>>>(h6, W6 + 64 * 64, l2off, l2srcA, W7, nullptr, h7);
    gconvL2_k<false, true ><<<C2, 256, 0, stream>>>(h7, W7 + 64 * 64, l2off, l2srcA, nullptr, g7, nullptr);

    outpool_k<<<16, 256, 0, stream>>>(g7, xo);
    linear_k<<<100, 64, 0, stream>>>(xo, Wl, bl, out);
}

// Round 18
// 388.018 us; speedup vs baseline: 1.0580x; 1.0580x over previous
//
#include <hip/hip_runtime.h>

#define NN 100000      // nodes
#define NE 1600000     // edges
#define C1 262144      // 64^3 cells (keyed as d2*64+child)
#define C2 4096        // 16^3 cells
#define BSH 7          // bucket shift (128 new-ids per bucket)
#define BSZ 128
#define NB 782         // ceil(NN/128)
#define PA_EDGES 4096
#define PA_IT (PA_EDGES / 256)
#define JMASK 0xFFFFF  // low 20 bits: compact j; bits 20..31: d2 of src cell
#define RMASK 0x1FFFF  // 17 bits: rank

// cell key layout: key = d2*64 + child, d2 = (x>>2)*256+(y>>2)*16+(z>>2),
// child = (x&3)*16+(y&3)*4+(z&3)
__device__ __forceinline__ void key2xyz(int key, float& x, float& y, float& z) {
    int d2 = key >> 6, ch = key & 63;
    x = (float)((((d2 >> 8) & 15) << 2) | (ch >> 4));
    y = (float)((((d2 >> 4) & 15) << 2) | ((ch >> 2) & 3));
    z = (float)(((d2 & 15) << 2) | (ch & 3));
}
__device__ __forceinline__ float4 max4(float4 a, float4 b) {
    return make_float4(fmaxf(a.x, b.x), fmaxf(a.y, b.y), fmaxf(a.z, b.z), fmaxf(a.w, b.w));
}
__device__ __forceinline__ float4 fma4(float s, float4 w, float4 acc) {
    return make_float4(s * w.x + acc.x, s * w.y + acc.y, s * w.z + acc.z, s * w.w + acc.w);
}

// ---------------- cell key of each node + node-per-cell histogram ----------------
__global__ __launch_bounds__(256)
void cidhist_k(const float* __restrict__ nodes, int* __restrict__ cid,
               int* __restrict__ cntN) {
    int i = blockIdx.x * 256 + threadIdx.x;
    if (i >= NN) return;
    int cx = min(max((int)floorf(nodes[3 * i]     * 0.25f), 0), 63);
    int cy = min(max((int)floorf(nodes[3 * i + 1] * 0.25f), 0), 63);
    int cz = min(max((int)floorf(nodes[3 * i + 2] * 0.25f), 0), 63);
    int d2 = ((cx >> 2) * 16 + (cy >> 2)) * 16 + (cz >> 2);
    int ch = ((cx & 3) * 4 + (cy & 3)) * 4 + (cz & 3);
    int key = (d2 << 6) | ch;
    cid[i] = key;
    atomicAdd(&cntN[key], 1);
}

// ---------------- generic exclusive scan: 2048/block. MODE 0: cnt[i]; MODE 1: cnt[i]>0 ----------------
template<int MODE>
__global__ __launch_bounds__(256)
void scan1_k(const int* __restrict__ cnt, int n, int* __restrict__ offs,
             int* __restrict__ bsum) {
    __shared__ int ws[4];
    int t = threadIdx.x, lane = t & 63, w = t >> 6;
    int base = blockIdx.x * 2048 + t * 8;
    int v[8]; int s = 0;
    #pragma unroll
    for (int i = 0; i < 8; ++i) {
        int raw = (base + i < n) ? cnt[base + i] : 0;
        v[i] = (MODE == 1) ? (raw > 0 ? 1 : 0) : raw;
        s += v[i];
    }
    int sc = s;
    #pragma unroll
    for (int off = 1; off < 64; off <<= 1) { int o = __shfl_up(sc, off); if (lane >= off) sc += o; }
    if (lane == 63) ws[w] = sc;
    __syncthreads();
    int wbase = 0;
    for (int i = 0; i < w; ++i) wbase += ws[i];
    int run = wbase + sc - s;
    #pragma unroll
    for (int i = 0; i < 8; ++i) { if (base + i < n) offs[base + i] = run; run += v[i]; }
    if (t == 255) bsum[blockIdx.x] = wbase + sc;
}

__global__ __launch_bounds__(256)
void scan2_k(int* __restrict__ bsum, int nb) {   // one block, nb <= 256
    __shared__ int ws[4];
    int t = threadIdx.x, lane = t & 63, w = t >> 6;
    int v = (t < nb) ? bsum[t] : 0;
    int sc = v;
    #pragma unroll
    for (int off = 1; off < 64; off <<= 1) { int o = __shfl_up(sc, off); if (lane >= off) sc += o; }
    if (lane == 63) ws[w] = sc;
    __syncthreads();
    int wbase = 0;
    for (int i = 0; i < w; ++i) wbase += ws[i];
    if (t < nb) bsum[t] = wbase + sc - v;
    if (t == 255) bsum[nb] = ws[0] + ws[1] + ws[2] + ws[3];
}

__global__ __launch_bounds__(256)
void scan3_k(int* __restrict__ offs, int n, const int* __restrict__ bsum, int nb) {
    int i = blockIdx.x * 256 + threadIdx.x;
    if (i < n) offs[i] += bsum[i >> 11];
    else if (i == n) offs[n] = bsum[nb];
}

// ---------------- occupied-cell compaction from offsOcc (deterministic, atomic-free) ----------------
__global__ __launch_bounds__(256)
void jlist_k(const int* __restrict__ offsOcc, int* __restrict__ jmap,
             int* __restrict__ oclist, int* __restrict__ ocount) {
    int c = blockIdx.x * 256 + threadIdx.x;
    if (c == 0) *ocount = offsOcc[C1];
    if (c >= C1) return;
    int pre = offsOcc[c];
    bool occ = offsOcc[c + 1] > pre;
    jmap[c] = occ ? pre : -1;
    if (occ) oclist[pre] = c;
}

// ---------------- node scatter: rank (new id) + nidx (old id by new id) ----------------
__global__ __launch_bounds__(256)
void nscatter_k(const int* __restrict__ cid, const int* __restrict__ offsN,
                int* __restrict__ cntN, int* __restrict__ rank, int* __restrict__ nidx) {
    int i = blockIdx.x * 256 + threadIdx.x;
    if (i >= NN) return;
    int c = cid[i];
    int pos = offsN[c] + atomicAdd(&cntN[c], -1) - 1;
    rank[i] = pos;
    nidx[pos] = i;
}

// ---------------- permute node data into new-id order ----------------
__global__ __launch_bounds__(256)
void permute_k(const int* __restrict__ nidx, const float* __restrict__ nodes,
               const float* __restrict__ feats, const int* __restrict__ cid,
               const int* __restrict__ jmap,
               float* __restrict__ pnodes, float* __restrict__ pfeat,
               int* __restrict__ jsrcP) {
    int d = blockIdx.x * 256 + threadIdx.x;
    if (d >= NN) return;
    int i = nidx[d];
    pnodes[3 * d]     = nodes[3 * i];
    pnodes[3 * d + 1] = nodes[3 * i + 1];
    pnodes[3 * d + 2] = nodes[3 * i + 2];
    pfeat[d] = feats[i];
    int c = cid[i];
    unsigned packed = (unsigned)jmap[c] | (((unsigned)c >> 6) << 20);  // j | d2<<20
    jsrcP[d] = (int)packed;
}

// ---------------- bucket histogram over rank[dst] (LDS pre-aggregated) ----------------
__global__ __launch_bounds__(256)
void bhist_k(const int* __restrict__ edst, const int* __restrict__ rank,
             int* __restrict__ btot) {
    __shared__ int h[NB];
    int tid = threadIdx.x;
    for (int i = tid; i < NB; i += 256) h[i] = 0;
    __syncthreads();
    int base = blockIdx.x * PA_EDGES;
    for (int i = 0; i < PA_IT; ++i) {
        int e = base + i * 256 + tid;
        if (e < NE) atomicAdd(&h[rank[edst[e]] >> BSH], 1);
    }
    __syncthreads();
    for (int i = tid; i < NB; i += 256) if (h[i]) atomicAdd(&btot[i], h[i]);
}

// one block: exclusive scan of NB (<=1024) bucket totals -> bbase[NB+1]; copy to cursor
__global__ __launch_bounds__(256)
void scanB_k(const int* __restrict__ btot, int* __restrict__ bbase,
             int* __restrict__ cursor) {
    __shared__ int ws[4];
    int t = threadIdx.x, lane = t & 63, w = t >> 6;
    int i0 = 4 * t;
    int v[4]; int s = 0;
    #pragma unroll
    for (int q = 0; q < 4; ++q) { v[q] = (i0 + q < NB) ? btot[i0 + q] : 0; s += v[q]; }
    int sc = s;
    #pragma unroll
    for (int off = 1; off < 64; off <<= 1) { int o = __shfl_up(sc, off); if (lane >= off) sc += o; }
    if (lane == 63) ws[w] = sc;
    __syncthreads();
    int wb = 0;
    for (int q = 0; q < w; ++q) wb += ws[q];
    int run = wb + sc - s;
    #pragma unroll
    for (int q = 0; q < 4; ++q) {
        if (i0 + q <= NB) { bbase[i0 + q] = run; if (i0 + q < NB) cursor[i0 + q] = run; }
        run += v[q];
    }
}

// ---------------- pass A: partition packed (rank_src | rd_low<<17) by dst bucket ----------------
__global__ __launch_bounds__(256)
void passA_k(const int* __restrict__ esrc, const int* __restrict__ edst,
             const int* __restrict__ rank, int* __restrict__ cursor,
             int* __restrict__ ebuf) {
    __shared__ int hist[NB];
    __shared__ int lofs[NB + 1];
    __shared__ int gbase[NB];
    __shared__ int cnt2[NB];
    __shared__ int stage[PA_EDGES];              // 16KB (packed)
    __shared__ unsigned short sbid[PA_EDGES];    // 8KB
    __shared__ int ws[4];
    int tid = threadIdx.x, lane = tid & 63, w = tid >> 6;
    for (int i = tid; i < NB; i += 256) { hist[i] = 0; cnt2[i] = 0; }
    __syncthreads();
    int base = blockIdx.x * PA_EDGES;
    for (int i = 0; i < PA_IT; ++i) {
        int e = base + i * 256 + tid;
        if (e < NE) atomicAdd(&hist[rank[edst[e]] >> BSH], 1);
    }
    __syncthreads();
    // exclusive scan hist -> lofs (4 per thread)
    int i0 = 4 * tid;
    int v[4]; int s = 0;
    #pragma unroll
    for (int q = 0; q < 4; ++q) { v[q] = (i0 + q < NB) ? hist[i0 + q] : 0; s += v[q]; }
    int sc = s;
    #pragma unroll
    for (int off = 1; off < 64; off <<= 1) { int o = __shfl_up(sc, off); if (lane >= off) sc += o; }
    if (lane == 63) ws[w] = sc;
    __syncthreads();
    int wb = 0;
    for (int q = 0; q < w; ++q) wb += ws[q];
    int run = wb + sc - s;
    #pragma unroll
    for (int q = 0; q < 4; ++q) {
        if (i0 + q <= NB) lofs[i0 + q] = run;
        run += v[q];
    }
    __syncthreads();
    for (int b = tid; b < NB; b += 256) {
        int c = hist[b];
        gbase[b] = c ? atomicAdd(&cursor[b], c) : 0;
    }
    __syncthreads();
    for (int i = 0; i < PA_IT; ++i) {
        int e = base + i * 256 + tid;
        if (e < NE) {
            int rd = rank[edst[e]], rs = rank[esrc[e]];
            int b = rd >> BSH;
            int p = lofs[b] + atomicAdd(&cnt2[b], 1);
            stage[p] = rs | ((rd & (BSZ - 1)) << 17);
            sbid[p] = (unsigned short)b;
        }
    }
    __syncthreads();
    int nval = min(PA_EDGES, NE - base);
    for (int k = tid; k < nval; k += 256) {
        int b = sbid[k];
        ebuf[gbase[b] + (k - lofs[b])] = stage[k];
    }
}

// ---------------- pass B: per-bucket final scatter; offs0 (new-id CSR); csrc fused ----------------
__global__ __launch_bounds__(256)
void passB_k(const int* __restrict__ ebuf, const int* __restrict__ bbase,
             const int* __restrict__ jsrcP,
             int* __restrict__ offs0, int* __restrict__ srcs0, int* __restrict__ csrc0) {
    __shared__ int cnt[BSZ];
    __shared__ int pos[BSZ];
    __shared__ int ws[4];
    int b = blockIdx.x, tid = threadIdx.x, lane = tid & 63, w = tid >> 6;
    int d0 = b << BSH;
    int range = min(BSZ, NN - d0);
    if (tid < BSZ) cnt[tid] = 0;
    __syncthreads();
    int r0 = bbase[b], r1 = bbase[b + 1];
    for (int k = r0 + tid; k < r1; k += 256) atomicAdd(&cnt[(ebuf[k] >> 17) & (BSZ - 1)], 1);
    __syncthreads();
    int v = (tid < BSZ) ? cnt[tid] : 0;
    int sc = v;
    #pragma unroll
    for (int off = 1; off < 64; off <<= 1) { int o = __shfl_up(sc, off); if (lane >= off) sc += o; }
    if (lane == 63) ws[w] = sc;
    __syncthreads();
    int wb = 0;
    for (int q = 0; q < w; ++q) wb += ws[q];
    int rel = wb + sc - v;                        // exclusive per-dst prefix
    if (tid < range) offs0[d0 + tid] = r0 + rel;
    if (tid == 0) offs0[min(d0 + BSZ, NN)] = r1;  // benign duplicate of next base
    if (tid < BSZ) pos[tid] = r0 + rel;
    __syncthreads();
    for (int k = r0 + tid; k < r1; k += 256) {
        int pk = ebuf[k];
        int di = (pk >> 17) & (BSZ - 1);
        int p = atomicAdd(&pos[di], 1);
        int rs = pk & RMASK;
        srcs0[p] = rs;
        csrc0[p] = jsrcP[rs];                     // packed j | d2<<20
    }
}

// ---------------- level-2 bitmap: contiguous edge slice -> LDS bitmap -> global ----------------
__global__ __launch_bounds__(256)
void mask_k(const int* __restrict__ offsN, const int* __restrict__ offs0,
            const int* __restrict__ csrc0,
            unsigned long long* __restrict__ mask, int* __restrict__ l2num) {
    __shared__ unsigned long long words[64];
    int d2 = blockIdx.x, tid = threadIdx.x;
    if (tid < 64) words[tid] = 0;
    __syncthreads();
    // all edges of d2's 64 child cells are one contiguous range (key ordering)
    int e0 = offs0[offsN[d2 << 6]];
    int e1 = offs0[offsN[(d2 + 1) << 6]];
    for (int t = e0 + tid; t < e1; t += 256) {
        int s2 = (int)(((unsigned)csrc0[t]) >> 20);
        atomicOr(&words[s2 >> 6], 1ull << (s2 & 63));
    }
    __syncthreads();
    if (tid < 64) {                                // wave 0 only
        unsigned long long wv = words[tid];
        mask[(size_t)d2 * 64 + tid] = wv;
        int pc = __popcll(wv);
        int sc = pc;
        #pragma unroll
        for (int off = 1; off < 64; off <<= 1) {
            int o = __shfl_up(sc, off);
            if (tid >= off) sc += o;
        }
        if (tid == 63) l2num[d2] = sc;
    }
}

// ---------------- emit compact per-d2 src list at deterministic offsets ----------------
__global__ __launch_bounds__(64)
void emit_k(const unsigned long long* __restrict__ mask, const int* __restrict__ l2off,
            int* __restrict__ l2src) {
    int d2 = blockIdx.x, tid = threadIdx.x;      // 64 threads
    unsigned long long wv = mask[(size_t)d2 * 64 + tid];
    int pc = __popcll(wv);
    int sc = pc;
    #pragma unroll
    for (int off = 1; off < 64; off <<= 1) {
        int o = __shfl_up(sc, off);
        if (tid >= off) sc += o;
    }
    int p = l2off[d2] + sc - pc;                 // exclusive prefix within d2
    while (wv) {
        int b = __builtin_ctzll(wv);
        wv &= wv - 1;
        l2src[p++] = (tid << 6) | b;
    }
}

// ---------------- level 0: h = f @ W_f + pos @ W_p (new-id space) ----------------
template<int CI, int CO>
__global__ __launch_bounds__(256)
void xform0_k(const float* __restrict__ pnodes, const float* __restrict__ f,
              const float* __restrict__ W, float* __restrict__ h) {
    __shared__ float sW[(CI + 3) * CO];
    for (int i = threadIdx.x; i < (CI + 3) * CO; i += 256) sW[i] = W[i];
    __syncthreads();
    int gid = blockIdx.x * 256 + threadIdx.x;
    int i = gid / CO, ch = gid - i * CO;
    if (i >= NN) return;
    float s = pnodes[3 * i] * sW[CI * CO + ch] + pnodes[3 * i + 1] * sW[(CI + 1) * CO + ch]
            + pnodes[3 * i + 2] * sW[(CI + 2) * CO + ch];
    #pragma unroll
    for (int k = 0; k < CI; ++k) s += f[(size_t)i * CI + k] * sW[k * CO + ch];
    h[(size_t)i * CO + ch] = s;
}

// fused: gather over W1 (8ch) + xform W2 (8->16) -> h2. Block covers 32 dst nodes.
__global__ __launch_bounds__(256)
void gatherL0f_k(const float* __restrict__ pnodes, const float* __restrict__ h1,
                 const float* __restrict__ W1pos,       // 3x8
                 const float* __restrict__ W2,          // 11x16
                 const int* __restrict__ offs, const int* __restrict__ srcs,
                 float* __restrict__ h2) {
    __shared__ float sW1[24];
    __shared__ float sW2[176];
    __shared__ float f1s[32][8];
    int tid = threadIdx.x;
    if (tid < 24) sW1[tid] = W1pos[tid];
    if (tid < 176) sW2[tid] = W2[tid];
    __syncthreads();
    int gid = blockIdx.x * 256 + tid;
    int d = gid >> 3, ch = gid & 7;
    int dbase = blockIdx.x * 32;
    if (d < NN) {
        float c = pnodes[3 * d] * sW1[ch] + pnodes[3 * d + 1] * sW1[8 + ch] + pnodes[3 * d + 2] * sW1[16 + ch];
        float m0 = c, m1 = c, m2 = c, m3 = c;
        int e0 = offs[d], e1 = offs[d + 1];
        int t = e0;
        for (; t + 4 <= e1; t += 4) {
            int s0 = srcs[t], s1 = srcs[t + 1], s2 = srcs[t + 2], s3 = srcs[t + 3];
            m0 = fmaxf(m0, h1[(size_t)s0 * 8 + ch]);
            m1 = fmaxf(m1, h1[(size_t)s1 * 8 + ch]);
            m2 = fmaxf(m2, h1[(size_t)s2 * 8 + ch]);
            m3 = fmaxf(m3, h1[(size_t)s3 * 8 + ch]);
        }
        for (; t < e1; ++t) m0 = fmaxf(m0, h1[(size_t)srcs[t] * 8 + ch]);
        f1s[d - dbase][ch] = fmaxf(fmaxf(m0, m1), fmaxf(m2, m3)) - c;
    }
    __syncthreads();
    // epilogue: h2[d][ch2] for 32 d x 16 ch2 = 512 outputs, 2 per thread
    #pragma unroll
    for (int rep = 0; rep < 2; ++rep) {
        int dL = (tid >> 4) + rep * 16, ch2 = tid & 15;
        int dg = dbase + dL;
        if (dg < NN) {
            float s = pnodes[3 * dg] * sW2[128 + ch2] + pnodes[3 * dg + 1] * sW2[144 + ch2]
                    + pnodes[3 * dg + 2] * sW2[160 + ch2];
            #pragma unroll
            for (int k = 0; k < 8; ++k) s += f1s[dL][k] * sW2[k * 16 + ch2];
            h2[(size_t)dg * 16 + ch2] = s;
        }
    }
}

// float4 gather, CO=16: 4 threads per dst node (channel quads)
__global__ __launch_bounds__(256)
void gatherL0v4_k(const float* __restrict__ pnodes, const float* __restrict__ h,
                  const float* __restrict__ Wpos,       // 3x16
                  const int* __restrict__ offs, const int* __restrict__ srcs,
                  float* __restrict__ out) {
    __shared__ float sW[48];
    int tid = threadIdx.x;
    if (tid < 48) sW[tid] = Wpos[tid];
    __syncthreads();
    int gid = blockIdx.x * 256 + tid;
    int d = gid >> 2, q = gid & 3;
    if (d >= NN) return;
    float px = pnodes[3 * d], py = pnodes[3 * d + 1], pz = pnodes[3 * d + 2];
    float4 w0 = *(const float4*)&sW[q * 4];
    float4 w1 = *(const float4*)&sW[16 + q * 4];
    float4 w2 = *(const float4*)&sW[32 + q * 4];
    float4 c = make_float4(px * w0.x + py * w1.x + pz * w2.x, px * w0.y + py * w1.y + pz * w2.y,
                           px * w0.z + py * w1.z + pz * w2.z, px * w0.w + py * w1.w + pz * w2.w);
    float4 m0 = c, m1 = c, m2 = c, m3 = c;       // no self-loop at level 0; empty -> 0
    int e0 = offs[d], e1 = offs[d + 1];
    int t = e0;
    for (; t + 4 <= e1; t += 4) {
        int s0 = srcs[t], s1 = srcs[t + 1], s2 = srcs[t + 2], s3 = srcs[t + 3];
        m0 = max4(m0, *(const float4*)&h[(size_t)s0 * 16 + q * 4]);
        m1 = max4(m1, *(const float4*)&h[(size_t)s1 * 16 + q * 4]);
        m2 = max4(m2, *(const float4*)&h[(size_t)s2 * 16 + q * 4]);
        m3 = max4(m3, *(const float4*)&h[(size_t)s3 * 16 + q * 4]);
    }
    for (; t < e1; ++t) m0 = max4(m0, *(const float4*)&h[(size_t)srcs[t] * 16 + q * 4]);
    float4 m = max4(max4(m0, m1), max4(m2, m3));
    *(float4*)&out[(size_t)d * 16 + q * 4] = make_float4(m.x - c.x, m.y - c.y, m.z - c.z, m.w - c.w);
}

// ---------------- level 1: fused pool(16ch) + xform W3 -> Hc ----------------
__global__ __launch_bounds__(256)
void pxformL1_k(const float* __restrict__ f2, const int* __restrict__ offsN,
                const int* __restrict__ oclist, const int* __restrict__ ocount,
                const float* __restrict__ W3, float* __restrict__ h) {
    __shared__ float sW[19 * 32];
    __shared__ float nf[8][16];
    for (int i = threadIdx.x; i < 19 * 32; i += 256) sW[i] = W3[i];
    int gid = blockIdx.x * 256 + threadIdx.x;
    int j = gid >> 5, ch = gid & 31;
    int lj = threadIdx.x >> 5;                   // 8 js per block
    bool valid = j < *ocount;
    int d = valid ? oclist[j] : 0;
    if (valid && ch < 16) {
        float m = 0.f;                           // f2 >= 0 (post-relu)
        int n0 = offsN[d], n1 = offsN[d + 1];
        for (int n = n0; n < n1; ++n) m = fmaxf(m, f2[(size_t)n * 16 + ch]);
        nf[lj][ch] = m;
    }
    __syncthreads();
    if (!valid) return;
    float px, py, pz;
    key2xyz(d, px, py, pz);
    float s = px * sW[16 * 32 + ch] + py * sW[17 * 32 + ch] + pz * sW[18 * 32 + ch];
    #pragma unroll
    for (int k = 0; k < 16; ++k) s += nf[lj][k] * sW[k * 32 + ch];
    h[(size_t)j * 32 + ch] = s;
}

// fused float4 gather(W3pos) + xform W4 (32->32) -> hnext (different buffer).
__global__ __launch_bounds__(256)
void gatherL1f_k(const float* __restrict__ h, const float* __restrict__ W3pos,
                 const float* __restrict__ W4,          // 35x32
                 const int* __restrict__ offsN, const int* __restrict__ offs0,
                 const int* __restrict__ csrc0,
                 const int* __restrict__ oclist, const int* __restrict__ ocount,
                 float* __restrict__ hnext) {
    __shared__ float sWp[96];
    __shared__ float sW4[35 * 32];
    __shared__ float gsT[32][33];                // [ch][lj], padded
    int tid = threadIdx.x;
    if (tid < 96) sWp[tid] = W3pos[tid];
    for (int i = tid; i < 35 * 32; i += 256) sW4[i] = W4[i];
    __syncthreads();
    int gid = blockIdx.x * 256 + tid;
    int j = gid >> 3, q = gid & 7;
    int lj = tid >> 3;
    bool valid = j < *ocount;
    float px = 0, py = 0, pz = 0;
    if (valid) {
        int d = oclist[j];
        key2xyz(d, px, py, pz);
        float4 w0 = *(const float4*)&sWp[q * 4];
        float4 w1 = *(const float4*)&sWp[32 + q * 4];
        float4 w2 = *(const float4*)&sWp[64 + q * 4];
        float4 c = make_float4(px * w0.x + py * w1.x + pz * w2.x, px * w0.y + py * w1.y + pz * w2.y,
                               px * w0.z + py * w1.z + pz * w2.z, px * w0.w + py * w1.w + pz * w2.w);
        float4 self = *(const float4*)&h[(size_t)j * 32 + q * 4];
        float4 m0 = max4(c, self), m1 = m0, m2 = m0, m3 = m0;   // self-loop
        int e0 = offs0[offsN[d]], e1 = offs0[offsN[d + 1]];
        int t = e0;
        for (; t + 4 <= e1; t += 4) {
            int s0 = csrc0[t] & JMASK, s1 = csrc0[t + 1] & JMASK;
            int s2 = csrc0[t + 2] & JMASK, s3 = csrc0[t + 3] & JMASK;
            m0 = max4(m0, *(const float4*)&h[(size_t)s0 * 32 + q * 4]);
            m1 = max4(m1, *(const float4*)&h[(size_t)s1 * 32 + q * 4]);
            m2 = max4(m2, *(const float4*)&h[(size_t)s2 * 32 + q * 4]);
            m3 = max4(m3, *(const float4*)&h[(size_t)s3 * 32 + q * 4]);
        }
        for (; t < e1; ++t) m0 = max4(m0, *(const float4*)&h[(size_t)(csrc0[t] & JMASK) * 32 + q * 4]);
        float4 m = max4(max4(m0, m1), max4(m2, m3));
        gsT[q * 4 + 0][lj] = m.x - c.x;
        gsT[q * 4 + 1][lj] = m.y - c.y;
        gsT[q * 4 + 2][lj] = m.z - c.z;
        gsT[q * 4 + 3][lj] = m.w - c.w;
    }
    __syncthreads();
    if (!valid) return;
    float4 s4;
    {
        float4 w0 = *(const float4*)&sW4[32 * 32 + q * 4];
        float4 w1 = *(const float4*)&sW4[33 * 32 + q * 4];
        float4 w2 = *(const float4*)&sW4[34 * 32 + q * 4];
        s4 = make_float4(px * w0.x + py * w1.x + pz * w2.x, px * w0.y + py * w1.y + pz * w2.y,
                         px * w0.z + py * w1.z + pz * w2.z, px * w0.w + py * w1.w + pz * w2.w);
    }
    #pragma unroll
    for (int k = 0; k < 32; ++k) {
        float g = gsT[k][lj];
        s4 = fma4(g, *(const float4*)&sW4[k * 32 + q * 4], s4);
    }
    *(float4*)&hnext[(size_t)j * 32 + q * 4] = s4;
}

// plain float4 flat gather (final level-1 layer)
__global__ __launch_bounds__(256)
void gatherL1_k(const float* __restrict__ h, const float* __restrict__ Wpos,
                const int* __restrict__ offsN, const int* __restrict__ offs0,
                const int* __restrict__ csrc0,
                const int* __restrict__ oclist, const int* __restrict__ ocount,
                float* __restrict__ g) {
    __shared__ float sW[96];
    int tid = threadIdx.x;
    if (tid < 96) sW[tid] = Wpos[tid];
    __syncthreads();
    int gid = blockIdx.x * 256 + tid;
    int j = gid >> 3, q = gid & 7;
    if (j >= *ocount) return;
    int d = oclist[j];
    float px, py, pz;
    key2xyz(d, px, py, pz);
    float4 w0 = *(const float4*)&sW[q * 4];
    float4 w1 = *(const float4*)&sW[32 + q * 4];
    float4 w2 = *(const float4*)&sW[64 + q * 4];
    float4 c = make_float4(px * w0.x + py * w1.x + pz * w2.x, px * w0.y + py * w1.y + pz * w2.y,
                           px * w0.z + py * w1.z + pz * w2.z, px * w0.w + py * w1.w + pz * w2.w);
    float4 self = *(const float4*)&h[(size_t)j * 32 + q * 4];
    float4 m0 = max4(c, self), m1 = m0, m2 = m0, m3 = m0;   // self-loop
    int e0 = offs0[offsN[d]], e1 = offs0[offsN[d + 1]];
    int t = e0;
    for (; t + 4 <= e1; t += 4) {
        int s0 = csrc0[t] & JMASK, s1 = csrc0[t + 1] & JMASK;
        int s2 = csrc0[t + 2] & JMASK, s3 = csrc0[t + 3] & JMASK;
        m0 = max4(m0, *(const float4*)&h[(size_t)s0 * 32 + q * 4]);
        m1 = max4(m1, *(const float4*)&h[(size_t)s1 * 32 + q * 4]);
        m2 = max4(m2, *(const float4*)&h[(size_t)s2 * 32 + q * 4]);
        m3 = max4(m3, *(const float4*)&h[(size_t)s3 * 32 + q * 4]);
    }
    for (; t < e1; ++t) m0 = max4(m0, *(const float4*)&h[(size_t)(csrc0[t] & JMASK) * 32 + q * 4]);
    float4 m = max4(max4(m0, m1), max4(m2, m3));
    *(float4*)&g[(size_t)j * 32 + q * 4] = make_float4(m.x - c.x, m.y - c.y, m.z - c.z, m.w - c.w);
}

// ---------------- level 2 (block per 16^3 cell) ----------------
// children of d2 are the contiguous key range [d2*64, d2*64+64)
__global__ __launch_bounds__(256)
void pool2x_k(const float* __restrict__ Gc, const int* __restrict__ jmap,
              const float* __restrict__ W5, float* __restrict__ h5) {
    __shared__ float part[8][32];
    __shared__ float nf2row[32];
    int d2 = blockIdx.x, tid = threadIdx.x;
    int x2 = d2 >> 8, y2 = (d2 >> 4) & 15, z2 = d2 & 15;
    int ch = tid & 31, grp = tid >> 5;                 // 8 grps x 8 children
    float m = 0.f;
    #pragma unroll
    for (int cc = 0; cc < 8; ++cc) {
        int cj = jmap[(d2 << 6) | (grp * 8 + cc)];
        if (cj >= 0) m = fmaxf(m, Gc[(size_t)cj * 32 + ch]);
    }
    part[grp][ch] = m;
    __syncthreads();
    if (tid < 32) {
        float mm = part[0][tid];
        #pragma unroll
        for (int g = 1; g < 8; ++g) mm = fmaxf(mm, part[g][tid]);
        nf2row[tid] = mm;
    }
    __syncthreads();
    if (tid < 64) {
        float s = x2 * W5[32 * 64 + tid] + y2 * W5[33 * 64 + tid] + z2 * W5[34 * 64 + tid];
        #pragma unroll
        for (int k = 0; k < 32; ++k) s += nf2row[k] * W5[k * 64 + tid];
        h5[(size_t)d2 * 64 + tid] = s;
    }
}

// level-2 gconv via flat adjacency list, float4 (+ optional fused next xform). One block per d2.
template<bool FUSE, bool WRITE_G>
__global__ __launch_bounds__(256)
void gconvL2_k(const float* __restrict__ h, const float* __restrict__ Wpos,
               const int* __restrict__ l2off, const int* __restrict__ l2src,
               const float* __restrict__ Wn,           // (64+3)x64, if FUSE
               float* __restrict__ gout, float* __restrict__ hnext) {
    __shared__ float red[16][64];
    __shared__ float grow[64];
    int d2 = blockIdx.x, tid = threadIdx.x;
    int x2 = d2 >> 8, y2 = (d2 >> 4) & 15, z2 = d2 & 15;
    int q = tid & 15, grp = tid >> 4;                  // 16 groups split the list
    int n0 = l2off[d2], num = l2off[d2 + 1] - n0;
    int per = (num + 15) >> 4;
    int s = n0 + grp * per;
    int e = min(n0 + num, s + per);
    float4 m0 = make_float4(-1e30f, -1e30f, -1e30f, -1e30f);
    float4 m1 = m0, m2 = m0, m3 = m0;
    int t = s;
    for (; t + 4 <= e; t += 4) {
        int s0 = l2src[t], s1 = l2src[t + 1], s2 = l2src[t + 2], s3 = l2src[t + 3];
        m0 = max4(m0, *(const float4*)&h[(size_t)s0 * 64 + q * 4]);
        m1 = max4(m1, *(const float4*)&h[(size_t)s1 * 64 + q * 4]);
        m2 = max4(m2, *(const float4*)&h[(size_t)s2 * 64 + q * 4]);
        m3 = max4(m3, *(const float4*)&h[(size_t)s3 * 64 + q * 4]);
    }
    for (; t < e; ++t) m0 = max4(m0, *(const float4*)&h[(size_t)l2src[t] * 64 + q * 4]);
    float4 m = max4(max4(m0, m1), max4(m2, m3));
    red[grp][q * 4 + 0] = m.x;
    red[grp][q * 4 + 1] = m.y;
    red[grp][q * 4 + 2] = m.z;
    red[grp][q * 4 + 3] = m.w;
    __syncthreads();
    if (tid < 64) {
        int ch = tid;
        float mm = red[0][ch];
        #pragma unroll
        for (int g = 1; g < 16; ++g) mm = fmaxf(mm, red[g][ch]);
        float c = x2 * Wpos[ch] + y2 * Wpos[64 + ch] + z2 * Wpos[128 + ch];
        mm = fmaxf(mm, fmaxf(c, h[(size_t)d2 * 64 + ch]));   // self-loop + empty
        float g = mm - c;
        if (WRITE_G) gout[(size_t)d2 * 64 + ch] = g;
        if (FUSE) grow[ch] = g;
    }
    if (FUSE) {
        __syncthreads();
        if (tid < 64) {
            float s2v = x2 * Wn[64 * 64 + tid] + y2 * Wn[65 * 64 + tid] + z2 * Wn[66 * 64 + tid];
            #pragma unroll
            for (int k = 0; k < 64; ++k) s2v += grow[k] * Wn[k * 64 + tid];
            hnext[(size_t)d2 * 64 + tid] = s2v;
        }
    }
}

// ---------------- output pool + linear ----------------
__global__ __launch_bounds__(256)
void outpool_k(const float* __restrict__ g7, float* __restrict__ xo) {
    int gid = blockIdx.x * 256 + threadIdx.x;
    if (gid >= 64 * 64) return;
    int oc = gid >> 6, ch = gid & 63;
    int cx = oc >> 4, cy = (oc >> 2) & 3, cz = oc & 3;
    float m = 0.f;
    for (int tc = 0; tc < 64; ++tc) {
        int i = tc >> 4, j = (tc >> 2) & 3, k = tc & 3;
        int d2 = ((cx * 4 + i) * 16 + (cy * 4 + j)) * 16 + (cz * 4 + k);
        m = fmaxf(m, g7[(size_t)d2 * 64 + ch]);
    }
    xo[(size_t)oc * 64 + ch] = m;
}

__global__ __launch_bounds__(64)
void linear_k(const float* __restrict__ xo, const float* __restrict__ Wl,
              const float* __restrict__ bl, float* __restrict__ out) {
    int j = blockIdx.x;
    float s = 0.f;
    for (int i = threadIdx.x; i < 4096; i += 64) s += xo[i] * Wl[(size_t)i * 100 + j];
    #pragma unroll
    for (int off = 32; off; off >>= 1) s += __shfl_down(s, off);
    if (threadIdx.x == 0) out[j] = s + bl[j];
}

extern "C" void kernel_launch(void* const* d_in, const int* in_sizes, int n_in,
                              void* d_out, int out_size, void* d_ws, size_t ws_size,
                              hipStream_t stream) {
    (void)in_sizes; (void)n_in; (void)out_size;
    const float* nodes = (const float*)d_in[0];
    const float* feats = (const float*)d_in[1];
    const int*   edges = (const int*)d_in[2];
    const int*   esrc  = edges;
    const int*   edst  = edges + NE;
    const float* W1 = (const float*)d_in[3];
    const float* W2 = (const float*)d_in[4];
    const float* W3 = (const float*)d_in[5];
    const float* W4 = (const float*)d_in[6];
    const float* W5 = (const float*)d_in[7];
    const float* W6 = (const float*)d_in[8];
    const float* W7 = (const float*)d_in[9];
    const float* Wl = (const float*)d_in[10];
    const float* bl = (const float*)d_in[11];
    float* out = (float*)d_out;

    char* ws = (char*)d_ws;
    size_t off = 0;
    auto alloc = [&](size_t bytes) { void* p = ws + off; off = (off + bytes + 255) & ~(size_t)255; return p; };
    // zero region: cntN + btot (one memset)
    int*   cntN    = (int*)alloc((size_t)C1 * 4);
    int*   btot    = (int*)alloc((size_t)NB * 4);
    size_t zero_bytes = off;
    int*   ocount  = (int*)alloc(4);
    int*   bsum   = (int*)alloc(260 * 4);
    int*   bbase  = (int*)alloc((size_t)(NB + 1) * 4);
    int*   cursor = (int*)alloc((size_t)NB * 4);
    int*   cid    = (int*)alloc((size_t)NN * 4);
    int*   rank   = (int*)alloc((size_t)NN * 4);
    int*   nidx   = (int*)alloc((size_t)NN * 4);
    int*   offsOcc= (int*)alloc((size_t)(C1 + 1) * 4);
    int*   offsN  = (int*)alloc((size_t)(C1 + 1) * 4);
    int*   offs0  = (int*)alloc((size_t)(NN + 1) * 4);
    int*   srcs0  = (int*)alloc((size_t)NE * 4);
    int*   csrc0  = (int*)alloc((size_t)NE * 4);
    int*   ebuf   = (int*)alloc((size_t)NE * 4);
    int*   oclist = (int*)alloc((size_t)NN * 4);
    int*   jmap   = (int*)alloc((size_t)C1 * 4);
    int*   jsrcP  = (int*)alloc((size_t)NN * 4);
    unsigned long long* mask = (unsigned long long*)alloc((size_t)C2 * 64 * 8);  // 2MB
    int*   l2num  = (int*)alloc((size_t)C2 * 4);
    int*   l2off  = (int*)alloc((size_t)(C2 + 1) * 4);
    int*   l2srcA = (int*)alloc((size_t)NE * 4);
    float* pnodes = (float*)alloc((size_t)NN * 3 * 4);
    float* pfeat  = (float*)alloc((size_t)NN * 4);
    float* A      = (float*)alloc((size_t)NN * 48 * 4);   // h1, h2, f2
    float* Hc     = (float*)alloc((size_t)NN * 32 * 4);
    float* Gc     = (float*)alloc((size_t)NN * 32 * 4);
    float* h5     = (float*)alloc((size_t)C2 * 64 * 4);
    float* h6     = (float*)alloc((size_t)C2 * 64 * 4);
    float* h7     = (float*)alloc((size_t)C2 * 64 * 4);
    float* g7     = (float*)alloc((size_t)C2 * 64 * 4);
    float* xo     = (float*)alloc((size_t)64 * 64 * 4);
    if (ws_size < off) return;

    float* h1 = A;                      // [NN][8]
    float* h2 = A + (size_t)NN * 16;    // [NN][16]
    float* f2 = A + (size_t)NN * 32;    // [NN][16]

    hipMemsetAsync(cntN, 0, zero_bytes, stream);

    auto gr = [](long long n) { return (int)((n + 255) / 256); };
    const int nbC1 = (C1 + 2047) / 2048;   // 128
    const int nbC2 = (C2 + 2047) / 2048;   // 2
    const int gPA  = (NE + PA_EDGES - 1) / PA_EDGES;  // 391

    // ---- connectivity build (key space, atomic-cursor-free) ----
    cidhist_k<<<gr(NN), 256, 0, stream>>>(nodes, cid, cntN);
    // occupancy compaction via boolean scan
    scan1_k<1><<<nbC1, 256, 0, stream>>>(cntN, C1, offsOcc, bsum);
    scan2_k<<<1, 256, 0, stream>>>(bsum, nbC1);
    scan3_k<<<gr(C1 + 1), 256, 0, stream>>>(offsOcc, C1, bsum, nbC1);
    jlist_k<<<gr(C1), 256, 0, stream>>>(offsOcc, jmap, oclist, ocount);
    // node CSR offsets
    scan1_k<0><<<nbC1, 256, 0, stream>>>(cntN, C1, offsN, bsum);
    scan2_k<<<1, 256, 0, stream>>>(bsum, nbC1);
    scan3_k<<<gr(C1 + 1), 256, 0, stream>>>(offsN, C1, bsum, nbC1);
    nscatter_k<<<gr(NN), 256, 0, stream>>>(cid, offsN, cntN, rank, nidx);
    permute_k<<<gr(NN), 256, 0, stream>>>(nidx, nodes, feats, cid, jmap, pnodes, pfeat, jsrcP);
    bhist_k<<<gPA, 256, 0, stream>>>(edst, rank, btot);
    scanB_k<<<1, 256, 0, stream>>>(btot, bbase, cursor);
    passA_k<<<gPA, 256, 0, stream>>>(esrc, edst, rank, cursor, ebuf);
    passB_k<<<NB, 256, 0, stream>>>(ebuf, bbase, jsrcP, offs0, srcs0, csrc0);
    // level-2 adjacency: bitmap -> scan -> deterministic emit
    mask_k<<<C2, 256, 0, stream>>>(offsN, offs0, csrc0, mask, l2num);
    scan1_k<0><<<nbC2, 256, 0, stream>>>(l2num, C2, l2off, bsum);
    scan2_k<<<1, 256, 0, stream>>>(bsum, nbC2);
    scan3_k<<<gr(C2 + 1), 256, 0, stream>>>(l2off, C2, bsum, nbC2);
    emit_k<<<C2, 64, 0, stream>>>(mask, l2off, l2srcA);

    // ---- level 0 (rank space) ----
    xform0_k<1, 8><<<gr((long long)NN * 8), 256, 0, stream>>>(pnodes, pfeat, W1, h1);
    gatherL0f_k<<<gr((long long)NN * 8), 256, 0, stream>>>(pnodes, h1, W1 + 1 * 8, W2, offs0, srcs0, h2);
    gatherL0v4_k<<<gr((long long)NN * 4), 256, 0, stream>>>(pnodes, h2, W2 + 8 * 16, offs0, srcs0, f2);

    // ---- level 1 (compact occupied cells, flat edge ranges; ping-pong Hc/Gc) ----
    pxformL1_k<<<gr((long long)NN * 32), 256, 0, stream>>>(f2, offsN, oclist, ocount, W3, Hc);
    gatherL1f_k<<<gr((long long)NN * 8), 256, 0, stream>>>(Hc, W3 + 16 * 32, W4, offsN, offs0, csrc0, oclist, ocount, Gc);
    gatherL1_k<<<gr((long long)NN * 8), 256, 0, stream>>>(Gc, W4 + 32 * 32, offsN, offs0, csrc0, oclist, ocount, Hc);

    // ---- level 2 (block per 16^3 cell, list-driven, fused) ----
    pool2x_k<<<C2, 256, 0, stream>>>(Hc, jmap, W5, h5);
    gconvL2_k<true,  false><<<C2, 256, 0, stream>>>(h5, W5 + 32 * 64, l2off, l2srcA, W6, nullptr, h6);
    gconvL2_k<true,  false><<<C2, 256, 0, stream>>>(h6, W6 + 64 * 64, l2off, l2srcA, W7, nullptr, h7);
    gconvL2_k<false, true ><<<C2, 256, 0, stream>>>(h7, W7 + 64 * 64, l2off, l2srcA, nullptr, g7, nullptr);

    outpool_k<<<16, 256, 0, stream>>>(g7, xo);
    linear_k<<<100, 64, 0, stream>>>(xo, Wl, bl, out);
}

// Round 19
// 377.813 us; speedup vs baseline: 1.0865x; 1.0270x over previous
//
#include <hip/hip_runtime.h>
#include <hip/hip_fp16.h>

#define NN 100000      // nodes
#define NE 1600000     // edges
#define C1 262144      // 64^3 cells (keyed as d2*64+child)
#define C2 4096        // 16^3 cells
#define BSH 7          // bucket shift (128 new-ids per bucket)
#define BSZ 128
#define NB 782         // ceil(NN/128)
#define PA_EDGES 4096
#define PA_IT (PA_EDGES / 256)
#define JMASK 0xFFFFF  // low 20 bits: compact j; bits 20..31: d2 of src cell
#define RMASK 0x1FFFF  // 17 bits: rank

// cell key layout: key = d2*64 + child
__device__ __forceinline__ void key2xyz(int key, float& x, float& y, float& z) {
    int d2 = key >> 6, ch = key & 63;
    x = (float)((((d2 >> 8) & 15) << 2) | (ch >> 4));
    y = (float)((((d2 >> 4) & 15) << 2) | ((ch >> 2) & 3));
    z = (float)(((d2 & 15) << 2) | (ch & 3));
}
__device__ __forceinline__ float4 max4(float4 a, float4 b) {
    return make_float4(fmaxf(a.x, b.x), fmaxf(a.y, b.y), fmaxf(a.z, b.z), fmaxf(a.w, b.w));
}
__device__ __forceinline__ float4 fma4(float s, float4 w, float4 acc) {
    return make_float4(s * w.x + acc.x, s * w.y + acc.y, s * w.z + acc.z, s * w.w + acc.w);
}
__device__ __forceinline__ float4 h4tof4(uint2 v) {
    __half2 a = *(__half2*)&v.x, b = *(__half2*)&v.y;
    float2 fa = __half22float2(a), fb = __half22float2(b);
    return make_float4(fa.x, fa.y, fb.x, fb.y);
}
__device__ __forceinline__ uint2 f4toh4(float4 f) {
    __half2 a = __floats2half2_rn(f.x, f.y), b = __floats2half2_rn(f.z, f.w);
    uint2 r;
    r.x = *(unsigned*)&a;
    r.y = *(unsigned*)&b;
    return r;
}

// ---------------- cell key of each node + node-per-cell histogram ----------------
__global__ __launch_bounds__(256)
void cidhist_k(const float* __restrict__ nodes, int* __restrict__ cid,
               int* __restrict__ cntN) {
    int i = blockIdx.x * 256 + threadIdx.x;
    if (i >= NN) return;
    int cx = min(max((int)floorf(nodes[3 * i]     * 0.25f), 0), 63);
    int cy = min(max((int)floorf(nodes[3 * i + 1] * 0.25f), 0), 63);
    int cz = min(max((int)floorf(nodes[3 * i + 2] * 0.25f), 0), 63);
    int d2 = ((cx >> 2) * 16 + (cy >> 2)) * 16 + (cz >> 2);
    int ch = ((cx & 3) * 4 + (cy & 3)) * 4 + (cz & 3);
    int key = (d2 << 6) | ch;
    cid[i] = key;
    atomicAdd(&cntN[key], 1);
}

// ---------------- generic exclusive scan: 2048/block. MODE 0: cnt[i]; MODE 1: cnt[i]>0 ----------------
template<int MODE>
__global__ __launch_bounds__(256)
void scan1_k(const int* __restrict__ cnt, int n, int* __restrict__ offs,
             int* __restrict__ bsum) {
    __shared__ int ws[4];
    int t = threadIdx.x, lane = t & 63, w = t >> 6;
    int base = blockIdx.x * 2048 + t * 8;
    int v[8]; int s = 0;
    #pragma unroll
    for (int i = 0; i < 8; ++i) {
        int raw = (base + i < n) ? cnt[base + i] : 0;
        v[i] = (MODE == 1) ? (raw > 0 ? 1 : 0) : raw;
        s += v[i];
    }
    int sc = s;
    #pragma unroll
    for (int off = 1; off < 64; off <<= 1) { int o = __shfl_up(sc, off); if (lane >= off) sc += o; }
    if (lane == 63) ws[w] = sc;
    __syncthreads();
    int wbase = 0;
    for (int i = 0; i < w; ++i) wbase += ws[i];
    int run = wbase + sc - s;
    #pragma unroll
    for (int i = 0; i < 8; ++i) { if (base + i < n) offs[base + i] = run; run += v[i]; }
    if (t == 255) bsum[blockIdx.x] = wbase + sc;
}

__global__ __launch_bounds__(256)
void scan2_k(int* __restrict__ bsum, int nb) {   // one block, nb <= 256
    __shared__ int ws[4];
    int t = threadIdx.x, lane = t & 63, w = t >> 6;
    int v = (t < nb) ? bsum[t] : 0;
    int sc = v;
    #pragma unroll
    for (int off = 1; off < 64; off <<= 1) { int o = __shfl_up(sc, off); if (lane >= off) sc += o; }
    if (lane == 63) ws[w] = sc;
    __syncthreads();
    int wbase = 0;
    for (int i = 0; i < w; ++i) wbase += ws[i];
    if (t < nb) bsum[t] = wbase + sc - v;
    if (t == 255) bsum[nb] = ws[0] + ws[1] + ws[2] + ws[3];
}

__global__ __launch_bounds__(256)
void scan3_k(int* __restrict__ offs, int n, const int* __restrict__ bsum, int nb) {
    int i = blockIdx.x * 256 + threadIdx.x;
    if (i < n) offs[i] += bsum[i >> 11];
    else if (i == n) offs[n] = bsum[nb];
}

// ---------------- occupied-cell compaction from offsOcc (deterministic, atomic-free) ----------------
__global__ __launch_bounds__(256)
void jlist_k(const int* __restrict__ offsOcc, int* __restrict__ jmap,
             int* __restrict__ oclist, int* __restrict__ ocount) {
    int c = blockIdx.x * 256 + threadIdx.x;
    if (c == 0) *ocount = offsOcc[C1];
    if (c >= C1) return;
    int pre = offsOcc[c];
    bool occ = offsOcc[c + 1] > pre;
    jmap[c] = occ ? pre : -1;
    if (occ) oclist[pre] = c;
}

// ---------------- node scatter: rank (new id) + nidx (old id by new id) ----------------
__global__ __launch_bounds__(256)
void nscatter_k(const int* __restrict__ cid, const int* __restrict__ offsN,
                int* __restrict__ cntN, int* __restrict__ rank, int* __restrict__ nidx) {
    int i = blockIdx.x * 256 + threadIdx.x;
    if (i >= NN) return;
    int c = cid[i];
    int pos = offsN[c] + atomicAdd(&cntN[c], -1) - 1;
    rank[i] = pos;
    nidx[pos] = i;
}

// ---------------- permute node data into new-id order ----------------
__global__ __launch_bounds__(256)
void permute_k(const int* __restrict__ nidx, const float* __restrict__ nodes,
               const float* __restrict__ feats, const int* __restrict__ cid,
               const int* __restrict__ jmap,
               float* __restrict__ pnodes, float* __restrict__ pfeat,
               int* __restrict__ jsrcP) {
    int d = blockIdx.x * 256 + threadIdx.x;
    if (d >= NN) return;
    int i = nidx[d];
    pnodes[3 * d]     = nodes[3 * i];
    pnodes[3 * d + 1] = nodes[3 * i + 1];
    pnodes[3 * d + 2] = nodes[3 * i + 2];
    pfeat[d] = feats[i];
    int c = cid[i];
    unsigned packed = (unsigned)jmap[c] | (((unsigned)c >> 6) << 20);  // j | d2<<20
    jsrcP[d] = (int)packed;
}

// ---------------- bucket histogram over rank[dst] (LDS pre-aggregated) ----------------
__global__ __launch_bounds__(256)
void bhist_k(const int* __restrict__ edst, const int* __restrict__ rank,
             int* __restrict__ btot) {
    __shared__ int h[NB];
    int tid = threadIdx.x;
    for (int i = tid; i < NB; i += 256) h[i] = 0;
    __syncthreads();
    int base = blockIdx.x * PA_EDGES;
    for (int i = 0; i < PA_IT; ++i) {
        int e = base + i * 256 + tid;
        if (e < NE) atomicAdd(&h[rank[edst[e]] >> BSH], 1);
    }
    __syncthreads();
    for (int i = tid; i < NB; i += 256) if (h[i]) atomicAdd(&btot[i], h[i]);
}

// one block: exclusive scan of NB (<=1024) bucket totals -> bbase[NB+1]; copy to cursor
__global__ __launch_bounds__(256)
void scanB_k(const int* __restrict__ btot, int* __restrict__ bbase,
             int* __restrict__ cursor) {
    __shared__ int ws[4];
    int t = threadIdx.x, lane = t & 63, w = t >> 6;
    int i0 = 4 * t;
    int v[4]; int s = 0;
    #pragma unroll
    for (int q = 0; q < 4; ++q) { v[q] = (i0 + q < NB) ? btot[i0 + q] : 0; s += v[q]; }
    int sc = s;
    #pragma unroll
    for (int off = 1; off < 64; off <<= 1) { int o = __shfl_up(sc, off); if (lane >= off) sc += o; }
    if (lane == 63) ws[w] = sc;
    __syncthreads();
    int wb = 0;
    for (int q = 0; q < w; ++q) wb += ws[q];
    int run = wb + sc - s;
    #pragma unroll
    for (int q = 0; q < 4; ++q) {
        if (i0 + q <= NB) { bbase[i0 + q] = run; if (i0 + q < NB) cursor[i0 + q] = run; }
        run += v[q];
    }
}

// ---------------- pass A: partition packed (rank_src | rd_low<<17) by dst bucket ----------------
__global__ __launch_bounds__(256)
void passA_k(const int* __restrict__ esrc, const int* __restrict__ edst,
             const int* __restrict__ rank, int* __restrict__ cursor,
             int* __restrict__ ebuf) {
    __shared__ int hist[NB];
    __shared__ int lofs[NB + 1];
    __shared__ int gbase[NB];
    __shared__ int cnt2[NB];
    __shared__ int stage[PA_EDGES];              // 16KB (packed)
    __shared__ unsigned short sbid[PA_EDGES];    // 8KB
    __shared__ int ws[4];
    int tid = threadIdx.x, lane = tid & 63, w = tid >> 6;
    for (int i = tid; i < NB; i += 256) { hist[i] = 0; cnt2[i] = 0; }
    __syncthreads();
    int base = blockIdx.x * PA_EDGES;
    for (int i = 0; i < PA_IT; ++i) {
        int e = base + i * 256 + tid;
        if (e < NE) atomicAdd(&hist[rank[edst[e]] >> BSH], 1);
    }
    __syncthreads();
    // exclusive scan hist -> lofs (4 per thread)
    int i0 = 4 * tid;
    int v[4]; int s = 0;
    #pragma unroll
    for (int q = 0; q < 4; ++q) { v[q] = (i0 + q < NB) ? hist[i0 + q] : 0; s += v[q]; }
    int sc = s;
    #pragma unroll
    for (int off = 1; off < 64; off <<= 1) { int o = __shfl_up(sc, off); if (lane >= off) sc += o; }
    if (lane == 63) ws[w] = sc;
    __syncthreads();
    int wb = 0;
    for (int q = 0; q < w; ++q) wb += ws[q];
    int run = wb + sc - s;
    #pragma unroll
    for (int q = 0; q < 4; ++q) {
        if (i0 + q <= NB) lofs[i0 + q] = run;
        run += v[q];
    }
    __syncthreads();
    for (int b = tid; b < NB; b += 256) {
        int c = hist[b];
        gbase[b] = c ? atomicAdd(&cursor[b], c) : 0;
    }
    __syncthreads();
    for (int i = 0; i < PA_IT; ++i) {
        int e = base + i * 256 + tid;
        if (e < NE) {
            int rd = rank[edst[e]], rs = rank[esrc[e]];
            int b = rd >> BSH;
            int p = lofs[b] + atomicAdd(&cnt2[b], 1);
            stage[p] = rs | ((rd & (BSZ - 1)) << 17);
            sbid[p] = (unsigned short)b;
        }
    }
    __syncthreads();
    int nval = min(PA_EDGES, NE - base);
    for (int k = tid; k < nval; k += 256) {
        int b = sbid[k];
        ebuf[gbase[b] + (k - lofs[b])] = stage[k];
    }
}

// ---------------- pass B: per-bucket final scatter; offs0 (new-id CSR); csrc fused ----------------
__global__ __launch_bounds__(256)
void passB_k(const int* __restrict__ ebuf, const int* __restrict__ bbase,
             const int* __restrict__ jsrcP,
             int* __restrict__ offs0, int* __restrict__ srcs0, int* __restrict__ csrc0) {
    __shared__ int cnt[BSZ];
    __shared__ int pos[BSZ];
    __shared__ int ws[4];
    int b = blockIdx.x, tid = threadIdx.x, lane = tid & 63, w = tid >> 6;
    int d0 = b << BSH;
    int range = min(BSZ, NN - d0);
    if (tid < BSZ) cnt[tid] = 0;
    __syncthreads();
    int r0 = bbase[b], r1 = bbase[b + 1];
    for (int k = r0 + tid; k < r1; k += 256) atomicAdd(&cnt[(ebuf[k] >> 17) & (BSZ - 1)], 1);
    __syncthreads();
    int v = (tid < BSZ) ? cnt[tid] : 0;
    int sc = v;
    #pragma unroll
    for (int off = 1; off < 64; off <<= 1) { int o = __shfl_up(sc, off); if (lane >= off) sc += o; }
    if (lane == 63) ws[w] = sc;
    __syncthreads();
    int wb = 0;
    for (int q = 0; q < w; ++q) wb += ws[q];
    int rel = wb + sc - v;                        // exclusive per-dst prefix
    if (tid < range) offs0[d0 + tid] = r0 + rel;
    if (tid == 0) offs0[min(d0 + BSZ, NN)] = r1;  // benign duplicate of next base
    if (tid < BSZ) pos[tid] = r0 + rel;
    __syncthreads();
    for (int k = r0 + tid; k < r1; k += 256) {
        int pk = ebuf[k];
        int di = (pk >> 17) & (BSZ - 1);
        int p = atomicAdd(&pos[di], 1);
        int rs = pk & RMASK;
        srcs0[p] = rs;
        csrc0[p] = jsrcP[rs];                     // packed j | d2<<20
    }
}

// ---------------- level-2 bitmap: contiguous edge slice -> LDS bitmap -> global ----------------
__global__ __launch_bounds__(256)
void mask_k(const int* __restrict__ offsN, const int* __restrict__ offs0,
            const int* __restrict__ csrc0,
            unsigned long long* __restrict__ mask, int* __restrict__ l2num) {
    __shared__ unsigned long long words[64];
    int d2 = blockIdx.x, tid = threadIdx.x;
    if (tid < 64) words[tid] = 0;
    __syncthreads();
    int e0 = offs0[offsN[d2 << 6]];
    int e1 = offs0[offsN[(d2 + 1) << 6]];
    for (int t = e0 + tid; t < e1; t += 256) {
        int s2 = (int)(((unsigned)csrc0[t]) >> 20);
        atomicOr(&words[s2 >> 6], 1ull << (s2 & 63));
    }
    __syncthreads();
    if (tid < 64) {                                // wave 0 only
        unsigned long long wv = words[tid];
        mask[(size_t)d2 * 64 + tid] = wv;
        int pc = __popcll(wv);
        int sc = pc;
        #pragma unroll
        for (int off = 1; off < 64; off <<= 1) {
            int o = __shfl_up(sc, off);
            if (tid >= off) sc += o;
        }
        if (tid == 63) l2num[d2] = sc;
    }
}

// ---------------- emit compact per-d2 src list at deterministic offsets ----------------
__global__ __launch_bounds__(64)
void emit_k(const unsigned long long* __restrict__ mask, const int* __restrict__ l2off,
            int* __restrict__ l2src) {
    int d2 = blockIdx.x, tid = threadIdx.x;      // 64 threads
    unsigned long long wv = mask[(size_t)d2 * 64 + tid];
    int pc = __popcll(wv);
    int sc = pc;
    #pragma unroll
    for (int off = 1; off < 64; off <<= 1) {
        int o = __shfl_up(sc, off);
        if (tid >= off) sc += o;
    }
    int p = l2off[d2] + sc - pc;                 // exclusive prefix within d2
    while (wv) {
        int b = __builtin_ctzll(wv);
        wv &= wv - 1;
        l2src[p++] = (tid << 6) | b;
    }
}

// ---------------- level 0: h = f @ W_f + pos @ W_p (new-id space) ----------------
template<int CI, int CO>
__global__ __launch_bounds__(256)
void xform0_k(const float* __restrict__ pnodes, const float* __restrict__ f,
              const float* __restrict__ W, float* __restrict__ h) {
    __shared__ float sW[(CI + 3) * CO];
    for (int i = threadIdx.x; i < (CI + 3) * CO; i += 256) sW[i] = W[i];
    __syncthreads();
    int gid = blockIdx.x * 256 + threadIdx.x;
    int i = gid / CO, ch = gid - i * CO;
    if (i >= NN) return;
    float s = pnodes[3 * i] * sW[CI * CO + ch] + pnodes[3 * i + 1] * sW[(CI + 1) * CO + ch]
            + pnodes[3 * i + 2] * sW[(CI + 2) * CO + ch];
    #pragma unroll
    for (int k = 0; k < CI; ++k) s += f[(size_t)i * CI + k] * sW[k * CO + ch];
    h[(size_t)i * CO + ch] = s;
}

// fused: gather over W1 (8ch) + xform W2 (8->16) -> h2. Block covers 32 dst nodes.
__global__ __launch_bounds__(256)
void gatherL0f_k(const float* __restrict__ pnodes, const float* __restrict__ h1,
                 const float* __restrict__ W1pos,       // 3x8
                 const float* __restrict__ W2,          // 11x16
                 const int* __restrict__ offs, const int* __restrict__ srcs,
                 float* __restrict__ h2) {
    __shared__ float sW1[24];
    __shared__ float sW2[176];
    __shared__ float f1s[32][8];
    int tid = threadIdx.x;
    if (tid < 24) sW1[tid] = W1pos[tid];
    if (tid < 176) sW2[tid] = W2[tid];
    __syncthreads();
    int gid = blockIdx.x * 256 + tid;
    int d = gid >> 3, ch = gid & 7;
    int dbase = blockIdx.x * 32;
    if (d < NN) {
        float c = pnodes[3 * d] * sW1[ch] + pnodes[3 * d + 1] * sW1[8 + ch] + pnodes[3 * d + 2] * sW1[16 + ch];
        float m0 = c, m1 = c, m2 = c, m3 = c;
        int e0 = offs[d], e1 = offs[d + 1];
        int t = e0;
        for (; t + 4 <= e1; t += 4) {
            int s0 = srcs[t], s1 = srcs[t + 1], s2 = srcs[t + 2], s3 = srcs[t + 3];
            m0 = fmaxf(m0, h1[(size_t)s0 * 8 + ch]);
            m1 = fmaxf(m1, h1[(size_t)s1 * 8 + ch]);
            m2 = fmaxf(m2, h1[(size_t)s2 * 8 + ch]);
            m3 = fmaxf(m3, h1[(size_t)s3 * 8 + ch]);
        }
        for (; t < e1; ++t) m0 = fmaxf(m0, h1[(size_t)srcs[t] * 8 + ch]);
        f1s[d - dbase][ch] = fmaxf(fmaxf(m0, m1), fmaxf(m2, m3)) - c;
    }
    __syncthreads();
    // epilogue: h2[d][ch2] for 32 d x 16 ch2 = 512 outputs, 2 per thread
    #pragma unroll
    for (int rep = 0; rep < 2; ++rep) {
        int dL = (tid >> 4) + rep * 16, ch2 = tid & 15;
        int dg = dbase + dL;
        if (dg < NN) {
            float s = pnodes[3 * dg] * sW2[128 + ch2] + pnodes[3 * dg + 1] * sW2[144 + ch2]
                    + pnodes[3 * dg + 2] * sW2[160 + ch2];
            #pragma unroll
            for (int k = 0; k < 8; ++k) s += f1s[dL][k] * sW2[k * 16 + ch2];
            h2[(size_t)dg * 16 + ch2] = s;
        }
    }
}

// float4 gather, CO=16: 4 threads per dst node (channel quads)
__global__ __launch_bounds__(256)
void gatherL0v4_k(const float* __restrict__ pnodes, const float* __restrict__ h,
                  const float* __restrict__ Wpos,       // 3x16
                  const int* __restrict__ offs, const int* __restrict__ srcs,
                  float* __restrict__ out) {
    __shared__ float sW[48];
    int tid = threadIdx.x;
    if (tid < 48) sW[tid] = Wpos[tid];
    __syncthreads();
    int gid = blockIdx.x * 256 + tid;
    int d = gid >> 2, q = gid & 3;
    if (d >= NN) return;
    float px = pnodes[3 * d], py = pnodes[3 * d + 1], pz = pnodes[3 * d + 2];
    float4 w0 = *(const float4*)&sW[q * 4];
    float4 w1 = *(const float4*)&sW[16 + q * 4];
    float4 w2 = *(const float4*)&sW[32 + q * 4];
    float4 c = make_float4(px * w0.x + py * w1.x + pz * w2.x, px * w0.y + py * w1.y + pz * w2.y,
                           px * w0.z + py * w1.z + pz * w2.z, px * w0.w + py * w1.w + pz * w2.w);
    float4 m0 = c, m1 = c, m2 = c, m3 = c;       // no self-loop at level 0; empty -> 0
    int e0 = offs[d], e1 = offs[d + 1];
    int t = e0;
    for (; t + 4 <= e1; t += 4) {
        int s0 = srcs[t], s1 = srcs[t + 1], s2 = srcs[t + 2], s3 = srcs[t + 3];
        m0 = max4(m0, *(const float4*)&h[(size_t)s0 * 16 + q * 4]);
        m1 = max4(m1, *(const float4*)&h[(size_t)s1 * 16 + q * 4]);
        m2 = max4(m2, *(const float4*)&h[(size_t)s2 * 16 + q * 4]);
        m3 = max4(m3, *(const float4*)&h[(size_t)s3 * 16 + q * 4]);
    }
    for (; t < e1; ++t) m0 = max4(m0, *(const float4*)&h[(size_t)srcs[t] * 16 + q * 4]);
    float4 m = max4(max4(m0, m1), max4(m2, m3));
    *(float4*)&out[(size_t)d * 16 + q * 4] = make_float4(m.x - c.x, m.y - c.y, m.z - c.z, m.w - c.w);
}

// ---------------- level 1: fused pool(16ch) + xform W3 -> Hh (fp16) ----------------
__global__ __launch_bounds__(256)
void pxformL1_k(const float* __restrict__ f2, const int* __restrict__ offsN,
                const int* __restrict__ oclist, const int* __restrict__ ocount,
                const float* __restrict__ W3, __half* __restrict__ hh) {
    __shared__ float sW[19 * 32];
    __shared__ float nf[8][16];
    for (int i = threadIdx.x; i < 19 * 32; i += 256) sW[i] = W3[i];
    int gid = blockIdx.x * 256 + threadIdx.x;
    int j = gid >> 5, ch = gid & 31;
    int lj = threadIdx.x >> 5;                   // 8 js per block
    bool valid = j < *ocount;
    int d = valid ? oclist[j] : 0;
    if (valid && ch < 16) {
        float m = 0.f;                           // f2 >= 0 (post-relu)
        int n0 = offsN[d], n1 = offsN[d + 1];
        for (int n = n0; n < n1; ++n) m = fmaxf(m, f2[(size_t)n * 16 + ch]);
        nf[lj][ch] = m;
    }
    __syncthreads();
    if (!valid) return;
    float px, py, pz;
    key2xyz(d, px, py, pz);
    float s = px * sW[16 * 32 + ch] + py * sW[17 * 32 + ch] + pz * sW[18 * 32 + ch];
    #pragma unroll
    for (int k = 0; k < 16; ++k) s += nf[lj][k] * sW[k * 32 + ch];
    hh[(size_t)j * 32 + ch] = __float2half(s);
}

// fused fp16 gather(W3pos) + xform W4 (32->32) -> fp16 hnext (different buffer).
__global__ __launch_bounds__(256)
void gatherL1f_k(const __half* __restrict__ hh, const float* __restrict__ W3pos,
                 const float* __restrict__ W4,          // 35x32
                 const int* __restrict__ offsN, const int* __restrict__ offs0,
                 const int* __restrict__ csrc0,
                 const int* __restrict__ oclist, const int* __restrict__ ocount,
                 __half* __restrict__ hnext) {
    __shared__ float sWp[96];
    __shared__ float sW4[35 * 32];
    __shared__ float gsT[32][33];                // [ch][lj], padded
    int tid = threadIdx.x;
    if (tid < 96) sWp[tid] = W3pos[tid];
    for (int i = tid; i < 35 * 32; i += 256) sW4[i] = W4[i];
    __syncthreads();
    int gid = blockIdx.x * 256 + tid;
    int j = gid >> 3, q = gid & 7;
    int lj = tid >> 3;
    bool valid = j < *ocount;
    float px = 0, py = 0, pz = 0;
    if (valid) {
        int d = oclist[j];
        key2xyz(d, px, py, pz);
        float4 w0 = *(const float4*)&sWp[q * 4];
        float4 w1 = *(const float4*)&sWp[32 + q * 4];
        float4 w2 = *(const float4*)&sWp[64 + q * 4];
        float4 c = make_float4(px * w0.x + py * w1.x + pz * w2.x, px * w0.y + py * w1.y + pz * w2.y,
                               px * w0.z + py * w1.z + pz * w2.z, px * w0.w + py * w1.w + pz * w2.w);
        float4 self = h4tof4(*(const uint2*)&hh[(size_t)j * 32 + q * 4]);
        float4 m0 = max4(c, self), m1 = m0, m2 = m0, m3 = m0;   // self-loop
        int e0 = offs0[offsN[d]], e1 = offs0[offsN[d + 1]];
        int t = e0;
        for (; t + 4 <= e1; t += 4) {
            int s0 = csrc0[t] & JMASK, s1 = csrc0[t + 1] & JMASK;
            int s2 = csrc0[t + 2] & JMASK, s3 = csrc0[t + 3] & JMASK;
            m0 = max4(m0, h4tof4(*(const uint2*)&hh[(size_t)s0 * 32 + q * 4]));
            m1 = max4(m1, h4tof4(*(const uint2*)&hh[(size_t)s1 * 32 + q * 4]));
            m2 = max4(m2, h4tof4(*(const uint2*)&hh[(size_t)s2 * 32 + q * 4]));
            m3 = max4(m3, h4tof4(*(const uint2*)&hh[(size_t)s3 * 32 + q * 4]));
        }
        for (; t < e1; ++t)
            m0 = max4(m0, h4tof4(*(const uint2*)&hh[(size_t)(csrc0[t] & JMASK) * 32 + q * 4]));
        float4 m = max4(max4(m0, m1), max4(m2, m3));
        gsT[q * 4 + 0][lj] = m.x - c.x;
        gsT[q * 4 + 1][lj] = m.y - c.y;
        gsT[q * 4 + 2][lj] = m.z - c.z;
        gsT[q * 4 + 3][lj] = m.w - c.w;
    }
    __syncthreads();
    if (!valid) return;
    float4 s4;
    {
        float4 w0 = *(const float4*)&sW4[32 * 32 + q * 4];
        float4 w1 = *(const float4*)&sW4[33 * 32 + q * 4];
        float4 w2 = *(const float4*)&sW4[34 * 32 + q * 4];
        s4 = make_float4(px * w0.x + py * w1.x + pz * w2.x, px * w0.y + py * w1.y + pz * w2.y,
                         px * w0.z + py * w1.z + pz * w2.z, px * w0.w + py * w1.w + pz * w2.w);
    }
    #pragma unroll
    for (int k = 0; k < 32; ++k) {
        float g = gsT[k][lj];
        s4 = fma4(g, *(const float4*)&sW4[k * 32 + q * 4], s4);
    }
    *(uint2*)&hnext[(size_t)j * 32 + q * 4] = f4toh4(s4);
}

// fp16 flat gather (final level-1 layer) -> fp32 output for pool2x
__global__ __launch_bounds__(256)
void gatherL1_k(const __half* __restrict__ hh, const float* __restrict__ Wpos,
                const int* __restrict__ offsN, const int* __restrict__ offs0,
                const int* __restrict__ csrc0,
                const int* __restrict__ oclist, const int* __restrict__ ocount,
                float* __restrict__ g) {
    __shared__ float sW[96];
    int tid = threadIdx.x;
    if (tid < 96) sW[tid] = Wpos[tid];
    __syncthreads();
    int gid = blockIdx.x * 256 + tid;
    int j = gid >> 3, q = gid & 7;
    if (j >= *ocount) return;
    int d = oclist[j];
    float px, py, pz;
    key2xyz(d, px, py, pz);
    float4 w0 = *(const float4*)&sW[q * 4];
    float4 w1 = *(const float4*)&sW[32 + q * 4];
    float4 w2 = *(const float4*)&sW[64 + q * 4];
    float4 c = make_float4(px * w0.x + py * w1.x + pz * w2.x, px * w0.y + py * w1.y + pz * w2.y,
                           px * w0.z + py * w1.z + pz * w2.z, px * w0.w + py * w1.w + pz * w2.w);
    float4 self = h4tof4(*(const uint2*)&hh[(size_t)j * 32 + q * 4]);
    float4 m0 = max4(c, self), m1 = m0, m2 = m0, m3 = m0;   // self-loop
    int e0 = offs0[offsN[d]], e1 = offs0[offsN[d + 1]];
    int t = e0;
    for (; t + 4 <= e1; t += 4) {
        int s0 = csrc0[t] & JMASK, s1 = csrc0[t + 1] & JMASK;
        int s2 = csrc0[t + 2] & JMASK, s3 = csrc0[t + 3] & JMASK;
        m0 = max4(m0, h4tof4(*(const uint2*)&hh[(size_t)s0 * 32 + q * 4]));
        m1 = max4(m1, h4tof4(*(const uint2*)&hh[(size_t)s1 * 32 + q * 4]));
        m2 = max4(m2, h4tof4(*(const uint2*)&hh[(size_t)s2 * 32 + q * 4]));
        m3 = max4(m3, h4tof4(*(const uint2*)&hh[(size_t)s3 * 32 + q * 4]));
    }
    for (; t < e1; ++t)
        m0 = max4(m0, h4tof4(*(const uint2*)&hh[(size_t)(csrc0[t] & JMASK) * 32 + q * 4]));
    float4 m = max4(max4(m0, m1), max4(m2, m3));
    *(float4*)&g[(size_t)j * 32 + q * 4] = make_float4(m.x - c.x, m.y - c.y, m.z - c.z, m.w - c.w);
}

// ---------------- level 2 (block per 16^3 cell) ----------------
// children of d2 are the contiguous key range [d2*64, d2*64+64)
__global__ __launch_bounds__(256)
void pool2x_k(const float* __restrict__ Gc, const int* __restrict__ jmap,
              const float* __restrict__ W5, float* __restrict__ h5) {
    __shared__ float part[8][32];
    __shared__ float nf2row[32];
    int d2 = blockIdx.x, tid = threadIdx.x;
    int x2 = d2 >> 8, y2 = (d2 >> 4) & 15, z2 = d2 & 15;
    int ch = tid & 31, grp = tid >> 5;                 // 8 grps x 8 children
    float m = 0.f;
    #pragma unroll
    for (int cc = 0; cc < 8; ++cc) {
        int cj = jmap[(d2 << 6) | (grp * 8 + cc)];
        if (cj >= 0) m = fmaxf(m, Gc[(size_t)cj * 32 + ch]);
    }
    part[grp][ch] = m;
    __syncthreads();
    if (tid < 32) {
        float mm = part[0][tid];
        #pragma unroll
        for (int g = 1; g < 8; ++g) mm = fmaxf(mm, part[g][tid]);
        nf2row[tid] = mm;
    }
    __syncthreads();
    if (tid < 64) {
        float s = x2 * W5[32 * 64 + tid] + y2 * W5[33 * 64 + tid] + z2 * W5[34 * 64 + tid];
        #pragma unroll
        for (int k = 0; k < 32; ++k) s += nf2row[k] * W5[k * 64 + tid];
        h5[(size_t)d2 * 64 + tid] = s;
    }
}

// level-2 gconv via flat adjacency list, float4 (+ optional fused next xform). One block per d2.
template<bool FUSE, bool WRITE_G>
__global__ __launch_bounds__(256)
void gconvL2_k(const float* __restrict__ h, const float* __restrict__ Wpos,
               const int* __restrict__ l2off, const int* __restrict__ l2src,
               const float* __restrict__ Wn,           // (64+3)x64, if FUSE
               float* __restrict__ gout, float* __restrict__ hnext) {
    __shared__ float red[16][64];
    __shared__ float grow[64];
    int d2 = blockIdx.x, tid = threadIdx.x;
    int x2 = d2 >> 8, y2 = (d2 >> 4) & 15, z2 = d2 & 15;
    int q = tid & 15, grp = tid >> 4;                  // 16 groups split the list
    int n0 = l2off[d2], num = l2off[d2 + 1] - n0;
    int per = (num + 15) >> 4;
    int s = n0 + grp * per;
    int e = min(n0 + num, s + per);
    float4 m0 = make_float4(-1e30f, -1e30f, -1e30f, -1e30f);
    float4 m1 = m0, m2 = m0, m3 = m0;
    int t = s;
    for (; t + 4 <= e; t += 4) {
        int s0 = l2src[t], s1 = l2src[t + 1], s2 = l2src[t + 2], s3 = l2src[t + 3];
        m0 = max4(m0, *(const float4*)&h[(size_t)s0 * 64 + q * 4]);
        m1 = max4(m1, *(const float4*)&h[(size_t)s1 * 64 + q * 4]);
        m2 = max4(m2, *(const float4*)&h[(size_t)s2 * 64 + q * 4]);
        m3 = max4(m3, *(const float4*)&h[(size_t)s3 * 64 + q * 4]);
    }
    for (; t < e; ++t) m0 = max4(m0, *(const float4*)&h[(size_t)l2src[t] * 64 + q * 4]);
    float4 m = max4(max4(m0, m1), max4(m2, m3));
    red[grp][q * 4 + 0] = m.x;
    red[grp][q * 4 + 1] = m.y;
    red[grp][q * 4 + 2] = m.z;
    red[grp][q * 4 + 3] = m.w;
    __syncthreads();
    if (tid < 64) {
        int ch = tid;
        float mm = red[0][ch];
        #pragma unroll
        for (int g = 1; g < 16; ++g) mm = fmaxf(mm, red[g][ch]);
        float c = x2 * Wpos[ch] + y2 * Wpos[64 + ch] + z2 * Wpos[128 + ch];
        mm = fmaxf(mm, fmaxf(c, h[(size_t)d2 * 64 + ch]));   // self-loop + empty
        float g = mm - c;
        if (WRITE_G) gout[(size_t)d2 * 64 + ch] = g;
        if (FUSE) grow[ch] = g;
    }
    if (FUSE) {
        __syncthreads();
        if (tid < 64) {
            float s2v = x2 * Wn[64 * 64 + tid] + y2 * Wn[65 * 64 + tid] + z2 * Wn[66 * 64 + tid];
            #pragma unroll
            for (int k = 0; k < 64; ++k) s2v += grow[k] * Wn[k * 64 + tid];
            hnext[(size_t)d2 * 64 + tid] = s2v;
        }
    }
}

// ---------------- output pool + linear ----------------
__global__ __launch_bounds__(256)
void outpool_k(const float* __restrict__ g7, float* __restrict__ xo) {
    int gid = blockIdx.x * 256 + threadIdx.x;
    if (gid >= 64 * 64) return;
    int oc = gid >> 6, ch = gid & 63;
    int cx = oc >> 4, cy = (oc >> 2) & 3, cz = oc & 3;
    float m = 0.f;
    for (int tc = 0; tc < 64; ++tc) {
        int i = tc >> 4, j = (tc >> 2) & 3, k = tc & 3;
        int d2 = ((cx * 4 + i) * 16 + (cy * 4 + j)) * 16 + (cz * 4 + k);
        m = fmaxf(m, g7[(size_t)d2 * 64 + ch]);
    }
    xo[(size_t)oc * 64 + ch] = m;
}

__global__ __launch_bounds__(64)
void linear_k(const float* __restrict__ xo, const float* __restrict__ Wl,
              const float* __restrict__ bl, float* __restrict__ out) {
    int j = blockIdx.x;
    float s = 0.f;
    for (int i = threadIdx.x; i < 4096; i += 64) s += xo[i] * Wl[(size_t)i * 100 + j];
    #pragma unroll
    for (int off = 32; off; off >>= 1) s += __shfl_down(s, off);
    if (threadIdx.x == 0) out[j] = s + bl[j];
}

extern "C" void kernel_launch(void* const* d_in, const int* in_sizes, int n_in,
                              void* d_out, int out_size, void* d_ws, size_t ws_size,
                              hipStream_t stream) {
    (void)in_sizes; (void)n_in; (void)out_size;
    const float* nodes = (const float*)d_in[0];
    const float* feats = (const float*)d_in[1];
    const int*   edges = (const int*)d_in[2];
    const int*   esrc  = edges;
    const int*   edst  = edges + NE;
    const float* W1 = (const float*)d_in[3];
    const float* W2 = (const float*)d_in[4];
    const float* W3 = (const float*)d_in[5];
    const float* W4 = (const float*)d_in[6];
    const float* W5 = (const float*)d_in[7];
    const float* W6 = (const float*)d_in[8];
    const float* W7 = (const float*)d_in[9];
    const float* Wl = (const float*)d_in[10];
    const float* bl = (const float*)d_in[11];
    float* out = (float*)d_out;

    char* ws = (char*)d_ws;
    size_t off = 0;
    auto alloc = [&](size_t bytes) { void* p = ws + off; off = (off + bytes + 255) & ~(size_t)255; return p; };
    // zero region: cntN + btot (one memset)
    int*   cntN    = (int*)alloc((size_t)C1 * 4);
    int*   btot    = (int*)alloc((size_t)NB * 4);
    size_t zero_bytes = off;
    int*   ocount  = (int*)alloc(4);
    int*   bsum   = (int*)alloc(260 * 4);
    int*   bbase  = (int*)alloc((size_t)(NB + 1) * 4);
    int*   cursor = (int*)alloc((size_t)NB * 4);
    int*   cid    = (int*)alloc((size_t)NN * 4);
    int*   rank   = (int*)alloc((size_t)NN * 4);
    int*   nidx   = (int*)alloc((size_t)NN * 4);
    int*   offsOcc= (int*)alloc((size_t)(C1 + 1) * 4);
    int*   offsN  = (int*)alloc((size_t)(C1 + 1) * 4);
    int*   offs0  = (int*)alloc((size_t)(NN + 1) * 4);
    int*   srcs0  = (int*)alloc((size_t)NE * 4);
    int*   csrc0  = (int*)alloc((size_t)NE * 4);
    int*   ebuf   = (int*)alloc((size_t)NE * 4);
    int*   oclist = (int*)alloc((size_t)NN * 4);
    int*   jmap   = (int*)alloc((size_t)C1 * 4);
    int*   jsrcP  = (int*)alloc((size_t)NN * 4);
    unsigned long long* mask = (unsigned long long*)alloc((size_t)C2 * 64 * 8);  // 2MB
    int*   l2num  = (int*)alloc((size_t)C2 * 4);
    int*   l2off  = (int*)alloc((size_t)(C2 + 1) * 4);
    int*   l2srcA = (int*)alloc((size_t)NE * 4);
    float* pnodes = (float*)alloc((size_t)NN * 3 * 4);
    float* pfeat  = (float*)alloc((size_t)NN * 4);
    float* A      = (float*)alloc((size_t)NN * 48 * 4);   // h1, h2, f2
    __half* Hh    = (__half*)alloc((size_t)NN * 32 * 2);  // fp16 level-1 tables
    __half* Gh    = (__half*)alloc((size_t)NN * 32 * 2);
    float* Hc     = (float*)alloc((size_t)NN * 32 * 4);   // fp32 final level-1 output
    float* h5     = (float*)alloc((size_t)C2 * 64 * 4);
    float* h6     = (float*)alloc((size_t)C2 * 64 * 4);
    float* h7     = (float*)alloc((size_t)C2 * 64 * 4);
    float* g7     = (float*)alloc((size_t)C2 * 64 * 4);
    float* xo     = (float*)alloc((size_t)64 * 64 * 4);
    if (ws_size < off) return;

    float* h1 = A;                      // [NN][8]
    float* h2 = A + (size_t)NN * 16;    // [NN][16]
    float* f2 = A + (size_t)NN * 32;    // [NN][16]

    hipMemsetAsync(cntN, 0, zero_bytes, stream);

    auto gr = [](long long n) { return (int)((n + 255) / 256); };
    const int nbC1 = (C1 + 2047) / 2048;   // 128
    const int nbC2 = (C2 + 2047) / 2048;   // 2
    const int gPA  = (NE + PA_EDGES - 1) / PA_EDGES;  // 391

    // ---- connectivity build (key space, atomic-cursor-free) ----
    cidhist_k<<<gr(NN), 256, 0, stream>>>(nodes, cid, cntN);
    scan1_k<1><<<nbC1, 256, 0, stream>>>(cntN, C1, offsOcc, bsum);
    scan2_k<<<1, 256, 0, stream>>>(bsum, nbC1);
    scan3_k<<<gr(C1 + 1), 256, 0, stream>>>(offsOcc, C1, bsum, nbC1);
    jlist_k<<<gr(C1), 256, 0, stream>>>(offsOcc, jmap, oclist, ocount);
    scan1_k<0><<<nbC1, 256, 0, stream>>>(cntN, C1, offsN, bsum);
    scan2_k<<<1, 256, 0, stream>>>(bsum, nbC1);
    scan3_k<<<gr(C1 + 1), 256, 0, stream>>>(offsN, C1, bsum, nbC1);
    nscatter_k<<<gr(NN), 256, 0, stream>>>(cid, offsN, cntN, rank, nidx);
    permute_k<<<gr(NN), 256, 0, stream>>>(nidx, nodes, feats, cid, jmap, pnodes, pfeat, jsrcP);
    bhist_k<<<gPA, 256, 0, stream>>>(edst, rank, btot);
    scanB_k<<<1, 256, 0, stream>>>(btot, bbase, cursor);
    passA_k<<<gPA, 256, 0, stream>>>(esrc, edst, rank, cursor, ebuf);
    passB_k<<<NB, 256, 0, stream>>>(ebuf, bbase, jsrcP, offs0, srcs0, csrc0);
    mask_k<<<C2, 256, 0, stream>>>(offsN, offs0, csrc0, mask, l2num);
    scan1_k<0><<<nbC2, 256, 0, stream>>>(l2num, C2, l2off, bsum);
    scan2_k<<<1, 256, 0, stream>>>(bsum, nbC2);
    scan3_k<<<gr(C2 + 1), 256, 0, stream>>>(l2off, C2, bsum, nbC2);
    emit_k<<<C2, 64, 0, stream>>>(mask, l2off, l2srcA);

    // ---- level 0 (rank space) ----
    xform0_k<1, 8><<<gr((long long)NN * 8), 256, 0, stream>>>(pnodes, pfeat, W1, h1);
    gatherL0f_k<<<gr((long long)NN * 8), 256, 0, stream>>>(pnodes, h1, W1 + 1 * 8, W2, offs0, srcs0, h2);
    gatherL0v4_k<<<gr((long long)NN * 4), 256, 0, stream>>>(pnodes, h2, W2 + 8 * 16, offs0, srcs0, f2);

    // ---- level 1 (fp16 tables: Hh -> Gh -> Hc) ----
    pxformL1_k<<<gr((long long)NN * 32), 256, 0, stream>>>(f2, offsN, oclist, ocount, W3, Hh);
    gatherL1f_k<<<gr((long long)NN * 8), 256, 0, stream>>>(Hh, W3 + 16 * 32, W4, offsN, offs0, csrc0, oclist, ocount, Gh);
    gatherL1_k<<<gr((long long)NN * 8), 256, 0, stream>>>(Gh, W4 + 32 * 32, offsN, offs0, csrc0, oclist, ocount, Hc);

    // ---- level 2 (block per 16^3 cell, list-driven, fused) ----
    pool2x_k<<<C2, 256, 0, stream>>>(Hc, jmap, W5, h5);
    gconvL2_k<true,  false><<<C2, 256, 0, stream>>>(h5, W5 + 32 * 64, l2off, l2srcA, W6, nullptr, h6);
    gconvL2_k<true,  false><<<C2, 256, 0, stream>>>(h6, W6 + 64 * 64, l2off, l2srcA, W7, nullptr, h7);
    gconvL2_k<false, true ><<<C2, 256, 0, stream>>>(h7, W7 + 64 * 64, l2off, l2srcA, nullptr, g7, nullptr);

    outpool_k<<<16, 256, 0, stream>>>(g7, xo);
    linear_k<<<100, 64, 0, stream>>>(xo, Wl, bl, out);
}